// Round 7
// baseline (11780.401 us; speedup 1.0000x reference)
//
#include <hip/hip_runtime.h>
#include <float.h>

#define NB 16
#define NP 4096
#define NM 1024
#define NK 32
#define CIN 64
#define C3 128
#define NGRP (NB*NM)
#define CNT (NB*NM*NK)
#define EPSV 1e-5f

// DPP cross-lane (VALU, ~4cyc) instead of __shfl (ds_bpermute, LDS latency).
// update_dpp(old=v, src=v): invalid/masked lanes yield own value (no-op merge).
#define DPPF(v, ctrl, rmask) __int_as_float(__builtin_amdgcn_update_dpp( \
        __float_as_int(v), __float_as_int(v), (ctrl), (rmask), 0xF, false))
#define DPPI(v, ctrl, rmask) __builtin_amdgcn_update_dpp((v), (v), (ctrl), (rmask), 0xF, false)

// Exact, contraction-free squared distance: matches numpy/JAX float32
// elementwise-square + left-to-right sum bit-for-bit (discrete selections
// in FPS/KNN depend on exact bit patterns).
__device__ __forceinline__ float sqdist3(float dx, float dy, float dz) {
    return __fadd_rn(__fadd_rn(__fmul_rn(dx, dx), __fmul_rn(dy, dy)), __fmul_rn(dz, dz));
}

__device__ __forceinline__ float dot4(float4 a, float4 b, float acc) {
    acc += a.x*b.x; acc += a.y*b.y; acc += a.z*b.z; acc += a.w*b.w; return acc;
}

// 64-lane max via DPP: row_shr 1/2/4/8 then row_bcast15 (rows 1,3) and
// row_bcast31 (rows 2,3); full max lands in lane 63, broadcast via readlane.
__device__ __forceinline__ float wave_max_bcast(float v) {
    v = fmaxf(v, DPPF(v, 0x111, 0xF));
    v = fmaxf(v, DPPF(v, 0x112, 0xF));
    v = fmaxf(v, DPPF(v, 0x114, 0xF));
    v = fmaxf(v, DPPF(v, 0x118, 0xF));
    v = fmaxf(v, DPPF(v, 0x142, 0xA));
    v = fmaxf(v, DPPF(v, 0x143, 0xC));
    return __int_as_float(__builtin_amdgcn_readlane(__float_as_int(v), 63));
}

// ---------------------------------------------------------------- FPS
// 256 threads = 4 waves; thread t owns contiguous points 16t..16t+15 in
// registers (lowest lane/wave == lowest global index -> tie-break free).
// Per iter: ILP dist update -> depth-4 tree argmax (coords carried) ->
// DPP wave max + ballot/ffs -> winner lane writes (val,x,y,z) to parity
// LDS slot -> one barrier -> 4-way merge. No bpermute anywhere.
__global__ __launch_bounds__(256) void fps_kernel(const float* __restrict__ xyz,
                                                  float* __restrict__ newxyz) {
    const int b = blockIdx.x;
    const int t = threadIdx.x;
    const int lane = t & 63, wv = t >> 6;
    const float* xb = xyz + (size_t)b * NP * 3;

    float px[16], py[16], pz[16], dist[16];
    {   // vectorized one-time load: 48 consecutive floats per thread
        const float4* s4 = (const float4*)(xb + t * 48);
        float4 q[12];
#pragma unroll
        for (int j = 0; j < 12; ++j) q[j] = s4[j];
        const float* f = (const float*)q;
#pragma unroll
        for (int j = 0; j < 16; ++j) {
            px[j] = f[j*3+0]; py[j] = f[j*3+1]; pz[j] = f[j*3+2];
            dist[j] = 1e10f;
        }
    }
    __shared__ float4 red[2][4];
    float cx = xb[0], cy = xb[1], cz = xb[2];   // first centroid = point 0

    for (int it = 0; it < NM; ++it) {
        if (t == 0) {
            size_t o = ((size_t)b * NM + it) * 3;
            newxyz[o+0] = cx; newxyz[o+1] = cy; newxyz[o+2] = cz;
        }
#pragma unroll
        for (int j = 0; j < 16; ++j) {
            float d = sqdist3(px[j]-cx, py[j]-cy, pz[j]-cz);
            dist[j] = fminf(dist[j], d);
        }
        // tree argmax; strict '>' takes right only when greater -> lowest idx on tie
        float tv[8], tx[8], ty[8], tz[8];
#pragma unroll
        for (int j = 0; j < 8; ++j) {
            bool tk = dist[2*j+1] > dist[2*j];
            tv[j] = tk ? dist[2*j+1] : dist[2*j];
            tx[j] = tk ? px[2*j+1] : px[2*j];
            ty[j] = tk ? py[2*j+1] : py[2*j];
            tz[j] = tk ? pz[2*j+1] : pz[2*j];
        }
#pragma unroll
        for (int j = 0; j < 4; ++j) {
            bool tk = tv[2*j+1] > tv[2*j];
            tv[j] = tk ? tv[2*j+1] : tv[2*j];
            tx[j] = tk ? tx[2*j+1] : tx[2*j];
            ty[j] = tk ? ty[2*j+1] : ty[2*j];
            tz[j] = tk ? tz[2*j+1] : tz[2*j];
        }
#pragma unroll
        for (int j = 0; j < 2; ++j) {
            bool tk = tv[2*j+1] > tv[2*j];
            tv[j] = tk ? tv[2*j+1] : tv[2*j];
            tx[j] = tk ? tx[2*j+1] : tx[2*j];
            ty[j] = tk ? ty[2*j+1] : ty[2*j];
            tz[j] = tk ? tz[2*j+1] : tz[2*j];
        }
        bool tkf = tv[1] > tv[0];
        float best = tkf ? tv[1] : tv[0];
        float bx = tkf ? tx[1] : tx[0];
        float by = tkf ? ty[1] : ty[0];
        float bz = tkf ? tz[1] : tz[0];

        float wmax = wave_max_bcast(best);
        unsigned long long mm = __ballot(best == wmax);
        int srcl = __ffsll((long long)mm) - 1;   // lowest lane with max == lowest idx
        if (lane == srcl) red[it & 1][wv] = make_float4(wmax, bx, by, bz);
        __syncthreads();
        float4 r = red[it & 1][0];
        float bv = r.x; cx = r.y; cy = r.z; cz = r.w;
#pragma unroll
        for (int w = 1; w < 4; ++w) {
            float4 rw = red[it & 1][w];
            if (rw.x > bv) { bv = rw.x; cx = rw.y; cy = rw.z; cz = rw.w; }  // strict: lowest wave wins
        }
    }
}

// ---------------------------------------------------------------- KNN
// Dist slots live in the owning thread's REGISTERS (each slot read/written
// only by its owner) -> no LDS dist array, no fill barrier, one barrier per
// round (parity-buffered rv/ri). Wave reduce = DPP pair-min with explicit
// lowest-index tie-break (result in lane 63).
__global__ __launch_bounds__(256) void knn_kernel(const float* __restrict__ xyz,
                                                  const float* __restrict__ newxyz,
                                                  int* __restrict__ knn_idx) {
    const int g = blockIdx.x;
    const int b = g >> 10;
    const int t = threadIdx.x;
    const int lane = t & 63, wv = t >> 6;
    const float* xb = xyz + (size_t)b * NP * 3;
    __shared__ float rv[2][4];
    __shared__ int   ri[2][4];
    float cx = newxyz[(size_t)g*3+0], cy = newxyz[(size_t)g*3+1], cz = newxyz[(size_t)g*3+2];
    float dv[16];
#pragma unroll
    for (int j = 0; j < 16; ++j) {
        int n = t + 256*j;
        dv[j] = sqdist3(cx - xb[n*3+0], cy - xb[n*3+1], cz - xb[n*3+2]);
    }
    for (int s = 0; s < NK; ++s) {
        // local tree argmin; strict '<' keeps left on tie -> lowest j -> lowest n
        float tv[8]; int ti[8];
#pragma unroll
        for (int j = 0; j < 8; ++j) {
            bool tk = dv[2*j+1] < dv[2*j];
            tv[j] = tk ? dv[2*j+1] : dv[2*j];
            ti[j] = tk ? (2*j+1) : (2*j);
        }
#pragma unroll
        for (int j = 0; j < 4; ++j) {
            bool tk = tv[2*j+1] < tv[2*j];
            tv[j] = tk ? tv[2*j+1] : tv[2*j];
            ti[j] = tk ? ti[2*j+1] : ti[2*j];
        }
#pragma unroll
        for (int j = 0; j < 2; ++j) {
            bool tk = tv[2*j+1] < tv[2*j];
            tv[j] = tk ? tv[2*j+1] : tv[2*j];
            ti[j] = tk ? ti[2*j+1] : ti[2*j];
        }
        bool tkf = tv[1] < tv[0];
        float best = tkf ? tv[1] : tv[0];
        int   bi   = t + ((tkf ? ti[1] : ti[0]) << 8);
        // DPP pair min-reduce with explicit idx tie-break; complete at lane 63
#define KSTEP(ctrl, rmask) { \
        float ov = DPPF(best, ctrl, rmask); \
        int   oi = DPPI(bi,   ctrl, rmask); \
        bool tk = (ov < best) || (ov == best && oi < bi); \
        best = tk ? ov : best; bi = tk ? oi : bi; }
        KSTEP(0x111, 0xF) KSTEP(0x112, 0xF) KSTEP(0x114, 0xF)
        KSTEP(0x118, 0xF) KSTEP(0x142, 0xA) KSTEP(0x143, 0xC)
#undef KSTEP
        if (lane == 63) { rv[s & 1][wv] = best; ri[s & 1][wv] = bi; }
        __syncthreads();
        float bv = rv[s & 1][0]; int bbi = ri[s & 1][0];
#pragma unroll
        for (int w = 1; w < 4; ++w) {
            float v2 = rv[s & 1][w]; int i2 = ri[s & 1][w];
            if (v2 < bv || (v2 == bv && i2 < bbi)) { bv = v2; bbi = i2; }
        }
        if (t == 0) knn_idx[(size_t)g*NK + s] = bbi;
        // owner invalidates its register slot (static indices only)
        bool own = (bbi & 255) == t;
        int  jb  = bbi >> 8;
#pragma unroll
        for (int j = 0; j < 16; ++j)
            dv[j] = (own && (j == jb)) ? FLT_MAX : dv[j];
    }
}

// ---------------------------------------------------------------- weight pre-pack
// Global packed layout (float4): w1[17][64] | w2[16][64] | w3[16][128], k-chunk major.
// w1's input dim permuted to [points(64) | norm(3) | 0-pad] to match our feat layout.
__global__ void repack_weights(const float* __restrict__ w1, const float* __restrict__ w2,
                               const float* __restrict__ w3, float4* __restrict__ wg) {
    int id = threadIdx.x + blockIdx.x * 256;
    if (id >= 4160) return;
    float4 v;
    if (id < 1088) {
        int c4 = id >> 6, col = id & 63;
        float e[4];
#pragma unroll
        for (int l = 0; l < 4; ++l) {
            int c = c4*4 + l;
            e[l] = (c < 64) ? w1[col*67 + c + 3] : ((c < 67) ? w1[col*67 + (c - 64)] : 0.f);
        }
        v = make_float4(e[0], e[1], e[2], e[3]);
    } else if (id < 2112) {
        int i2 = id - 1088; int c4 = i2 >> 6, col = i2 & 63;
        const float* p = w2 + col*64 + c4*4;
        v = make_float4(p[0], p[1], p[2], p[3]);
    } else {
        int i3 = id - 2112; int c4 = i3 >> 7, col = i3 & 127;
        const float* p = w3 + col*64 + c4*4;
        v = make_float4(p[0], p[1], p[2], p[3]);
    }
    wg[id] = v;
}

// ---------------------------------------------------------------- BN finalize
__global__ void finalize_kernel(const float* __restrict__ gstats, const float* __restrict__ gamma,
                                const float* __restrict__ beta, float* __restrict__ a_out,
                                float* __restrict__ s_out, int C) {
    int c = threadIdx.x + blockIdx.x * blockDim.x;
    if (c < C) {
        float mean = gstats[c] * (1.0f / CNT);
        float var  = gstats[C + c] * (1.0f / CNT) - mean * mean;
        float a = gamma[c] * rsqrtf(var + EPSV);
        a_out[c] = a;
        s_out[c] = beta[c] - mean * a;
    }
}

// ---------------------------------------------------------------- BN3+relu on z3 extremes
// out = relu(a3*zmax+s3) if a3>=0 else relu(a3*zmin+s3). Bit-identical to the
// full stage-4 recompute: *,+ by/with positive a and relu are fp-monotone.
__global__ __launch_bounds__(256) void apply_bn3(const float* __restrict__ zext,
                                                 const float* __restrict__ ab,
                                                 float* __restrict__ out_np) {
    int k = blockIdx.x * 256 + threadIdx.x;        // f4 index over (B*M, 128)
    if (k >= NGRP * 32) return;
    int g = k >> 5, q = k & 31;
    float4 mx = ((const float4*)zext)[g*64 + q];
    float4 mn = ((const float4*)zext)[g*64 + 32 + q];
    float4 a  = ((const float4*)ab)[64 + q];       // a3
    float4 s  = ((const float4*)ab)[96 + q];       // s3
    float4 r;
    r.x = fmaxf(a.x * (a.x >= 0.f ? mx.x : mn.x) + s.x, 0.f);
    r.y = fmaxf(a.y * (a.y >= 0.f ? mx.y : mn.y) + s.y, 0.f);
    r.z = fmaxf(a.z * (a.z >= 0.f ? mx.z : mn.z) + s.z, 0.f);
    r.w = fmaxf(a.w * (a.w >= 0.f ? mx.w : mn.w) + s.w, 0.f);
    ((float4*)out_np)[k] = r;
}

// ---------------------------------------------------------------- fused per-group chain
// Weights LDS-resident (stage-conditional). feat/hbuf XOR-swizzled.
// STAGE 3 additionally reduces per-group per-channel max/min of raw z3 into
// zext (if non-null), making STAGE 4 unnecessary.
template<int STAGE>
__global__ __launch_bounds__(256, (STAGE <= 1) ? 4 : ((STAGE == 2) ? 2 : 1))
void chain_kernel(const float* __restrict__ xyz, const float* __restrict__ points,
                  const float* __restrict__ newxyz, const int* __restrict__ knn_idx,
                  const float4* __restrict__ wg,
                  const float* __restrict__ b1, const float* __restrict__ b2,
                  const float* __restrict__ b3, const float* __restrict__ ab,
                  float* __restrict__ gstats, float* __restrict__ out_np,
                  float* __restrict__ zext)
{
    constexpr int W1F4 = 17*64;                       // 1088
    constexpr int W2F4 = (STAGE >= 2) ? 16*64 : 0;    // 1024
    constexpr int W3F4 = (STAGE >= 3) ? 16*128 : 0;   // 2048
    constexpr int WTOT = W1F4 + W2F4 + W3F4;
    constexpr int FEATF4 = 32*24;                     // 768 (24 slots/row)
    constexpr int HBF4 = (STAGE >= 2) ? 32*16 : 0;    // 512 (16 slots/row)
    __shared__ __align__(16) float4 smem[WTOT + FEATF4 + HBF4 + 72];  // +72f4: stats(256f)+kidx(32i)
    float4* featb = smem + WTOT;
    float*  featF = (float*)featb;
    float4* hb    = featb + FEATF4;
    float*  hbF   = (float*)hb;
    float*  statL = (float*)(smem + WTOT + FEATF4 + HBF4);
    int*    kidx  = (int*)(statL + 256);

    const int t = threadIdx.x;
    const int rowg = t & 7;
    const int colg = t >> 3;

    for (int i = t; i < WTOT; i += 256) smem[i] = wg[i];
    if (STAGE < 4) statL[t] = 0.f;

    float bias1[2], a1v[2], s1v[2], bias2[2], a2v[2], s2v[2];
    float bias3[4], a3v[4], s3v[4];
#pragma unroll
    for (int j = 0; j < 2; ++j) {
        int c = colg + 32*j;
        bias1[j] = b1[c]; bias2[j] = b2[c];
        if (STAGE >= 2) { a1v[j] = ab[c];       s1v[j] = ab[64 + c]; }
        if (STAGE >= 3) { a2v[j] = ab[128 + c]; s2v[j] = ab[192 + c]; }
    }
#pragma unroll
    for (int j = 0; j < 4; ++j) {
        int c = colg + 32*j;
        bias3[j] = b3[c];
        if (STAGE == 4) { a3v[j] = ab[256 + c]; s3v[j] = ab[384 + c]; }
    }

    for (int g = blockIdx.x; g < NGRP; g += gridDim.x) {
        const int b = g >> 10;
        __syncthreads();                               // protect smem reuse across groups
        if (t < 32) kidx[t] = knn_idx[(size_t)g*NK + t];
        __syncthreads();
        // ---- gather: points as float4 (coalesced 256B/row), then norm + pad
        const float* pb = points + (size_t)b * NP * CIN;
        {
            int r0 = t >> 4, c4g = t & 15;
            featb[r0*24 + (c4g ^ (r0>>2))] = *(const float4*)(pb + (size_t)kidx[r0]*CIN + c4g*4);
            int r1 = r0 + 16;
            featb[r1*24 + (c4g ^ (r1>>2))] = *(const float4*)(pb + (size_t)kidx[r1]*CIN + c4g*4);
        }
        const float* xb = xyz + (size_t)b * NP * 3;
        if (t < 96) {
            int r = t / 3, d = t - r*3;
            featF[r*96 + ((16 ^ (r>>2))<<2) + d] = xb[kidx[r]*3 + d] - newxyz[(size_t)g*3 + d];
        }
        if (t < 32) featF[t*96 + ((16 ^ (t>>2))<<2) + 3] = 0.f;
        __syncthreads();

        // ---- layer 1: K=68 (17 chunks)
        float acc[2][4];
#pragma unroll
        for (int i = 0; i < 4; ++i) { acc[0][i] = bias1[0]; acc[1][i] = bias1[1]; }
#pragma unroll 4
        for (int c4 = 0; c4 < 17; ++c4) {
            float4 w0 = smem[c4*64 + colg];
            float4 w1v = smem[c4*64 + colg + 32];
#pragma unroll
            for (int i = 0; i < 4; ++i) {
                float4 f = featb[(rowg*4 + i)*24 + (c4 ^ rowg)];
                acc[0][i] = dot4(f, w0, acc[0][i]);
                acc[1][i] = dot4(f, w1v, acc[1][i]);
            }
        }
        if (STAGE == 1) {
#pragma unroll
            for (int j = 0; j < 2; ++j) {
                float p = acc[j][0]+acc[j][1]+acc[j][2]+acc[j][3];
                float q = acc[j][0]*acc[j][0]+acc[j][1]*acc[j][1]+acc[j][2]*acc[j][2]+acc[j][3]*acc[j][3];
#pragma unroll
                for (int off = 4; off > 0; off >>= 1) { p += __shfl_down(p, off, 8); q += __shfl_down(q, off, 8); }
                if (rowg == 0) { int c = colg + 32*j; statL[c] += p; statL[128 + c] += q; }
            }
            continue;
        }
        // h1 -> hbuf
#pragma unroll
        for (int j = 0; j < 2; ++j) {
            int col = colg + 32*j;
            int so = (((col>>2) ^ rowg) << 2) + (col & 3);
#pragma unroll
            for (int i = 0; i < 4; ++i)
                hbF[(rowg*4 + i)*64 + so] = fmaxf(acc[j][i]*a1v[j] + s1v[j], 0.f);
        }
        __syncthreads();

        // ---- layer 2: K=64 (16 chunks), input hbuf
#pragma unroll
        for (int i = 0; i < 4; ++i) { acc[0][i] = bias2[0]; acc[1][i] = bias2[1]; }
#pragma unroll 4
        for (int c4 = 0; c4 < 16; ++c4) {
            float4 w0 = smem[W1F4 + c4*64 + colg];
            float4 w1v = smem[W1F4 + c4*64 + colg + 32];
#pragma unroll
            for (int i = 0; i < 4; ++i) {
                float4 f = hb[(rowg*4 + i)*16 + (c4 ^ rowg)];
                acc[0][i] = dot4(f, w0, acc[0][i]);
                acc[1][i] = dot4(f, w1v, acc[1][i]);
            }
        }
        if (STAGE == 2) {
#pragma unroll
            for (int j = 0; j < 2; ++j) {
                float p = acc[j][0]+acc[j][1]+acc[j][2]+acc[j][3];
                float q = acc[j][0]*acc[j][0]+acc[j][1]*acc[j][1]+acc[j][2]*acc[j][2]+acc[j][3]*acc[j][3];
#pragma unroll
                for (int off = 4; off > 0; off >>= 1) { p += __shfl_down(p, off, 8); q += __shfl_down(q, off, 8); }
                if (rowg == 0) { int c = colg + 32*j; statL[c] += p; statL[128 + c] += q; }
            }
            continue;
        }
        // h2 -> feat buffer (ping-pong)
#pragma unroll
        for (int j = 0; j < 2; ++j) {
            int col = colg + 32*j;
            int so = (((col>>2) ^ rowg) << 2) + (col & 3);
#pragma unroll
            for (int i = 0; i < 4; ++i)
                featF[(rowg*4 + i)*96 + so] = fmaxf(acc[j][i]*a2v[j] + s2v[j], 0.f);
        }
        __syncthreads();

        // ---- layer 3: K=64, 128 cols (TN=4), input feat buffer
        float acc3[4][4];
#pragma unroll
        for (int i = 0; i < 4; ++i)
#pragma unroll
            for (int j = 0; j < 4; ++j) acc3[j][i] = bias3[j];
#pragma unroll 4
        for (int c4 = 0; c4 < 16; ++c4) {
            float4 wa = smem[W1F4 + W2F4 + c4*128 + colg];
            float4 wb = smem[W1F4 + W2F4 + c4*128 + colg + 32];
            float4 wc = smem[W1F4 + W2F4 + c4*128 + colg + 64];
            float4 wd = smem[W1F4 + W2F4 + c4*128 + colg + 96];
#pragma unroll
            for (int i = 0; i < 4; ++i) {
                float4 f = featb[(rowg*4 + i)*24 + (c4 ^ rowg)];
                acc3[0][i] = dot4(f, wa, acc3[0][i]);
                acc3[1][i] = dot4(f, wb, acc3[1][i]);
                acc3[2][i] = dot4(f, wc, acc3[2][i]);
                acc3[3][i] = dot4(f, wd, acc3[3][i]);
            }
        }
        if (STAGE == 3) {
#pragma unroll
            for (int j = 0; j < 4; ++j) {
                float p = acc3[j][0]+acc3[j][1]+acc3[j][2]+acc3[j][3];
                float q = acc3[j][0]*acc3[j][0]+acc3[j][1]*acc3[j][1]+acc3[j][2]*acc3[j][2]+acc3[j][3]*acc3[j][3];
#pragma unroll
                for (int off = 4; off > 0; off >>= 1) { p += __shfl_down(p, off, 8); q += __shfl_down(q, off, 8); }
                if (rowg == 0) { int c = colg + 32*j; statL[c] += p; statL[128 + c] += q; }
            }
            if (zext) {   // per-group per-channel raw-z3 max/min -> stage 4 elimination
                float mx[4], mn[4];
#pragma unroll
                for (int j = 0; j < 4; ++j) {
                    mx[j] = fmaxf(fmaxf(acc3[j][0], acc3[j][1]), fmaxf(acc3[j][2], acc3[j][3]));
                    mn[j] = fminf(fminf(acc3[j][0], acc3[j][1]), fminf(acc3[j][2], acc3[j][3]));
                }
#pragma unroll
                for (int off = 4; off > 0; off >>= 1)
#pragma unroll
                    for (int j = 0; j < 4; ++j) {
                        mx[j] = fmaxf(mx[j], __shfl_down(mx[j], off, 8));
                        mn[j] = fminf(mn[j], __shfl_down(mn[j], off, 8));
                    }
                if (rowg == 0) {
#pragma unroll
                    for (int j = 0; j < 4; ++j) {
                        zext[(size_t)g*256 + colg + 32*j]       = mx[j];
                        zext[(size_t)g*256 + 128 + colg + 32*j] = mn[j];
                    }
                }
            }
            continue;
        }
        // ---- STAGE 4 (fallback only): bn+relu, max over 32 rows, write
        float mx[4];
#pragma unroll
        for (int j = 0; j < 4; ++j) {
            float h0 = fmaxf(acc3[j][0]*a3v[j] + s3v[j], 0.f);
            float h1 = fmaxf(acc3[j][1]*a3v[j] + s3v[j], 0.f);
            float h2 = fmaxf(acc3[j][2]*a3v[j] + s3v[j], 0.f);
            float h3 = fmaxf(acc3[j][3]*a3v[j] + s3v[j], 0.f);
            mx[j] = fmaxf(fmaxf(h0, h1), fmaxf(h2, h3));
        }
#pragma unroll
        for (int off = 4; off > 0; off >>= 1)
#pragma unroll
            for (int j = 0; j < 4; ++j) mx[j] = fmaxf(mx[j], __shfl_down(mx[j], off, 8));
        if (rowg == 0) {
#pragma unroll
            for (int j = 0; j < 4; ++j)
                out_np[(size_t)g*C3 + colg + 32*j] = mx[j];
        }
    }
    if (STAGE < 4) {
        __syncthreads();
        constexpr int C = (STAGE == 3) ? 128 : 64;
        if (t < C) { atomicAdd(&gstats[t], statL[t]); atomicAdd(&gstats[C + t], statL[128 + t]); }
    }
}

// ---------------------------------------------------------------- launch
extern "C" void kernel_launch(void* const* d_in, const int* in_sizes, int n_in,
                              void* d_out, int out_size, void* d_ws, size_t ws_size,
                              hipStream_t stream) {
    (void)in_sizes; (void)n_in; (void)out_size;
    const float* xyz    = (const float*)d_in[0];
    const float* points = (const float*)d_in[1];
    const float* w1  = (const float*)d_in[2];
    const float* b1  = (const float*)d_in[3];
    const float* g1  = (const float*)d_in[4];
    const float* be1 = (const float*)d_in[5];
    const float* w2  = (const float*)d_in[6];
    const float* b2  = (const float*)d_in[7];
    const float* g2  = (const float*)d_in[8];
    const float* be2 = (const float*)d_in[9];
    const float* w3  = (const float*)d_in[10];
    const float* b3  = (const float*)d_in[11];
    const float* g3  = (const float*)d_in[12];
    const float* be3 = (const float*)d_in[13];

    float* out = (float*)d_out;
    float* newxyz = out;                          // (B,M,3)
    float* out_np = out + (size_t)NB*NM*3;        // (B,M,128)

    int*    knn_idx = (int*)d_ws;                                 // 524288 ints
    float*  stats   = (float*)(knn_idx + (size_t)NB*NM*NK);       // 512 f
    float*  ab      = stats + 512;                                // 512 f
    float4* wg      = (float4*)(ab + 512);                        // 4160 f4
    float*  zext    = (float*)(wg + 4160);                        // 16384*256 f (16.8 MB)
    const size_t need = (size_t)((char*)(zext + (size_t)NGRP*256) - (char*)d_ws);
    const bool ext = ws_size >= need;
    float* zarg = ext ? zext : nullptr;

    hipMemsetAsync(stats, 0, 512*sizeof(float), stream);
    repack_weights<<<17, 256, 0, stream>>>(w1, w2, w3, wg);
    fps_kernel<<<NB, 256, 0, stream>>>(xyz, newxyz);
    knn_kernel<<<NB*NM, 256, 0, stream>>>(xyz, newxyz, knn_idx);

    chain_kernel<1><<<1024, 256, 0, stream>>>(xyz, points, newxyz, knn_idx, wg, b1, b2, b3,
                                              ab, stats + 0, out_np, nullptr);
    finalize_kernel<<<1, 64, 0, stream>>>(stats + 0, g1, be1, ab + 0, ab + 64, 64);
    chain_kernel<2><<<1024, 256, 0, stream>>>(xyz, points, newxyz, knn_idx, wg, b1, b2, b3,
                                              ab, stats + 128, out_np, nullptr);
    finalize_kernel<<<1, 64, 0, stream>>>(stats + 128, g2, be2, ab + 128, ab + 192, 64);
    chain_kernel<3><<<1024, 256, 0, stream>>>(xyz, points, newxyz, knn_idx, wg, b1, b2, b3,
                                              ab, stats + 256, out_np, zarg);
    finalize_kernel<<<1, 128, 0, stream>>>(stats + 256, g3, be3, ab + 256, ab + 384, 128);
    if (ext) {
        apply_bn3<<<2048, 256, 0, stream>>>(zext, ab, out_np);
    } else {
        chain_kernel<4><<<1024, 256, 0, stream>>>(xyz, points, newxyz, knn_idx, wg, b1, b2, b3,
                                                  ab, stats, out_np, nullptr);
    }
}

// Round 9
// 5067.893 us; speedup vs baseline: 2.3245x; 2.3245x over previous
//
#include <hip/hip_runtime.h>
#include <float.h>

#define NB 16
#define NP 4096
#define NM 1024
#define NK 32
#define CIN 64
#define C3 128
#define NGRP (NB*NM)
#define CNT (NB*NM*NK)
#define EPSV 1e-5f

// DPP cross-lane — used ONLY in knn (verified fast there; the fps DPP variant
// regressed 12x in round 7 and was reverted to __shfl mechanics).
#define DPPF(v, ctrl, rmask) __int_as_float(__builtin_amdgcn_update_dpp( \
        __float_as_int(v), __float_as_int(v), (ctrl), (rmask), 0xF, false))
#define DPPI(v, ctrl, rmask) __builtin_amdgcn_update_dpp((v), (v), (ctrl), (rmask), 0xF, false)

// Exact, contraction-free squared distance: matches numpy/JAX float32
// elementwise-square + left-to-right sum bit-for-bit (discrete selections
// in FPS/KNN depend on exact bit patterns).
__device__ __forceinline__ float sqdist3(float dx, float dy, float dz) {
    return __fadd_rn(__fadd_rn(__fmul_rn(dx, dx), __fmul_rn(dy, dy)), __fmul_rn(dz, dz));
}

__device__ __forceinline__ float dot4(float4 a, float4 b, float acc) {
    acc += a.x*b.x; acc += a.y*b.y; acc += a.z*b.z; acc += a.w*b.w; return acc;
}

// ---------------------------------------------------------------- FPS
// Round-6-verified mechanics (875us): value-only __shfl_xor butterfly,
// ballot/ffs winner lane, 3 shfl coord pulls, lane-0 parity-LDS store, one
// barrier, 4-way merge. Round-7 addition kept: depth-4 ILP tree for the
// LOCAL argmax (replaces 16-deep serial compare chain; no cross-lane ops).
__global__ __launch_bounds__(256) void fps_kernel(const float* __restrict__ xyz,
                                                  float* __restrict__ newxyz) {
    const int b = blockIdx.x;
    const int t = threadIdx.x;
    const int lane = t & 63, wv = t >> 6;
    const float* xb = xyz + (size_t)b * NP * 3;

    float px[16], py[16], pz[16], dist[16];
    {   // vectorized one-time load: 48 consecutive floats per thread
        const float4* s4 = (const float4*)(xb + t * 48);
        float4 q[12];
#pragma unroll
        for (int j = 0; j < 12; ++j) q[j] = s4[j];
        const float* f = (const float*)q;
#pragma unroll
        for (int j = 0; j < 16; ++j) {
            px[j] = f[j*3+0]; py[j] = f[j*3+1]; pz[j] = f[j*3+2];
            dist[j] = 1e10f;
        }
    }
    __shared__ float4 red[2][4];
    float cx = xb[0], cy = xb[1], cz = xb[2];   // first centroid = point 0

    for (int it = 0; it < NM; ++it) {
        if (t == 0) {
            size_t o = ((size_t)b * NM + it) * 3;
            newxyz[o+0] = cx; newxyz[o+1] = cy; newxyz[o+2] = cz;
        }
#pragma unroll
        for (int j = 0; j < 16; ++j) {
            float d = sqdist3(px[j]-cx, py[j]-cy, pz[j]-cz);
            dist[j] = fminf(dist[j], d);
        }
        // local tree argmax; strict '>' takes right only when greater -> lowest idx on tie
        float tv[8], tx[8], ty[8], tz[8];
#pragma unroll
        for (int j = 0; j < 8; ++j) {
            bool tk = dist[2*j+1] > dist[2*j];
            tv[j] = tk ? dist[2*j+1] : dist[2*j];
            tx[j] = tk ? px[2*j+1] : px[2*j];
            ty[j] = tk ? py[2*j+1] : py[2*j];
            tz[j] = tk ? pz[2*j+1] : pz[2*j];
        }
#pragma unroll
        for (int j = 0; j < 4; ++j) {
            bool tk = tv[2*j+1] > tv[2*j];
            tv[j] = tk ? tv[2*j+1] : tv[2*j];
            tx[j] = tk ? tx[2*j+1] : tx[2*j];
            ty[j] = tk ? ty[2*j+1] : ty[2*j];
            tz[j] = tk ? tz[2*j+1] : tz[2*j];
        }
#pragma unroll
        for (int j = 0; j < 2; ++j) {
            bool tk = tv[2*j+1] > tv[2*j];
            tv[j] = tk ? tv[2*j+1] : tv[2*j];
            tx[j] = tk ? tx[2*j+1] : tx[2*j];
            ty[j] = tk ? ty[2*j+1] : ty[2*j];
            tz[j] = tk ? tz[2*j+1] : tz[2*j];
        }
        bool tkf = tv[1] > tv[0];
        float best = tkf ? tv[1] : tv[0];
        float bx = tkf ? tx[1] : tx[0];
        float by = tkf ? ty[1] : ty[0];
        float bz = tkf ? tz[1] : tz[0];

        // wave max (value only) — verified __shfl_xor butterfly
        float wmax = best;
#pragma unroll
        for (int off = 32; off > 0; off >>= 1)
            wmax = fmaxf(wmax, __shfl_xor(wmax, off, 64));
        // lowest lane holding the max == lowest global index in this wave
        unsigned long long mm = __ballot(best == wmax);
        int srcl = __ffsll((long long)mm) - 1;
        float wx = __shfl(bx, srcl, 64);
        float wy = __shfl(by, srcl, 64);
        float wz = __shfl(bz, srcl, 64);
        if (lane == 0) red[it & 1][wv] = make_float4(wmax, wx, wy, wz);
        __syncthreads();
        float4 r = red[it & 1][0];
        float bv = r.x; cx = r.y; cy = r.z; cz = r.w;
#pragma unroll
        for (int w = 1; w < 4; ++w) {
            float4 rw = red[it & 1][w];
            if (rw.x > bv) { bv = rw.x; cx = rw.y; cy = rw.z; cz = rw.w; }  // strict: lowest wave wins
        }
    }
}

// ---------------------------------------------------------------- KNN
// (round-7 verified) Dist slots in owning thread's registers -> no LDS dist
// array, one barrier per round (parity rv/ri). DPP pair-min reduce with
// explicit lowest-index tie-break (result in lane 63).
__global__ __launch_bounds__(256) void knn_kernel(const float* __restrict__ xyz,
                                                  const float* __restrict__ newxyz,
                                                  int* __restrict__ knn_idx) {
    const int g = blockIdx.x;
    const int b = g >> 10;
    const int t = threadIdx.x;
    const int lane = t & 63, wv = t >> 6;
    const float* xb = xyz + (size_t)b * NP * 3;
    __shared__ float rv[2][4];
    __shared__ int   ri[2][4];
    float cx = newxyz[(size_t)g*3+0], cy = newxyz[(size_t)g*3+1], cz = newxyz[(size_t)g*3+2];
    float dv[16];
#pragma unroll
    for (int j = 0; j < 16; ++j) {
        int n = t + 256*j;
        dv[j] = sqdist3(cx - xb[n*3+0], cy - xb[n*3+1], cz - xb[n*3+2]);
    }
    for (int s = 0; s < NK; ++s) {
        float tv[8]; int ti[8];
#pragma unroll
        for (int j = 0; j < 8; ++j) {
            bool tk = dv[2*j+1] < dv[2*j];
            tv[j] = tk ? dv[2*j+1] : dv[2*j];
            ti[j] = tk ? (2*j+1) : (2*j);
        }
#pragma unroll
        for (int j = 0; j < 4; ++j) {
            bool tk = tv[2*j+1] < tv[2*j];
            tv[j] = tk ? tv[2*j+1] : tv[2*j];
            ti[j] = tk ? ti[2*j+1] : ti[2*j];
        }
#pragma unroll
        for (int j = 0; j < 2; ++j) {
            bool tk = tv[2*j+1] < tv[2*j];
            tv[j] = tk ? tv[2*j+1] : tv[2*j];
            ti[j] = tk ? ti[2*j+1] : ti[2*j];
        }
        bool tkf = tv[1] < tv[0];
        float best = tkf ? tv[1] : tv[0];
        int   bi   = t + ((tkf ? ti[1] : ti[0]) << 8);
#define KSTEP(ctrl, rmask) { \
        float ov = DPPF(best, ctrl, rmask); \
        int   oi = DPPI(bi,   ctrl, rmask); \
        bool tk = (ov < best) || (ov == best && oi < bi); \
        best = tk ? ov : best; bi = tk ? oi : bi; }
        KSTEP(0x111, 0xF) KSTEP(0x112, 0xF) KSTEP(0x114, 0xF)
        KSTEP(0x118, 0xF) KSTEP(0x142, 0xA) KSTEP(0x143, 0xC)
#undef KSTEP
        if (lane == 63) { rv[s & 1][wv] = best; ri[s & 1][wv] = bi; }
        __syncthreads();
        float bv = rv[s & 1][0]; int bbi = ri[s & 1][0];
#pragma unroll
        for (int w = 1; w < 4; ++w) {
            float v2 = rv[s & 1][w]; int i2 = ri[s & 1][w];
            if (v2 < bv || (v2 == bv && i2 < bbi)) { bv = v2; bbi = i2; }
        }
        if (t == 0) knn_idx[(size_t)g*NK + s] = bbi;
        bool own = (bbi & 255) == t;
        int  jb  = bbi >> 8;
#pragma unroll
        for (int j = 0; j < 16; ++j)
            dv[j] = (own && (j == jb)) ? FLT_MAX : dv[j];
    }
}

// ---------------------------------------------------------------- weight pre-pack
__global__ void repack_weights(const float* __restrict__ w1, const float* __restrict__ w2,
                               const float* __restrict__ w3, float4* __restrict__ wg) {
    int id = threadIdx.x + blockIdx.x * 256;
    if (id >= 4160) return;
    float4 v;
    if (id < 1088) {
        int c4 = id >> 6, col = id & 63;
        float e[4];
#pragma unroll
        for (int l = 0; l < 4; ++l) {
            int c = c4*4 + l;
            e[l] = (c < 64) ? w1[col*67 + c + 3] : ((c < 67) ? w1[col*67 + (c - 64)] : 0.f);
        }
        v = make_float4(e[0], e[1], e[2], e[3]);
    } else if (id < 2112) {
        int i2 = id - 1088; int c4 = i2 >> 6, col = i2 & 63;
        const float* p = w2 + col*64 + c4*4;
        v = make_float4(p[0], p[1], p[2], p[3]);
    } else {
        int i3 = id - 2112; int c4 = i3 >> 7, col = i3 & 127;
        const float* p = w3 + col*64 + c4*4;
        v = make_float4(p[0], p[1], p[2], p[3]);
    }
    wg[id] = v;
}

// ---------------------------------------------------------------- BN finalize
__global__ void finalize_kernel(const float* __restrict__ gstats, const float* __restrict__ gamma,
                                const float* __restrict__ beta, float* __restrict__ a_out,
                                float* __restrict__ s_out, int C) {
    int c = threadIdx.x + blockIdx.x * blockDim.x;
    if (c < C) {
        float mean = gstats[c] * (1.0f / CNT);
        float var  = gstats[C + c] * (1.0f / CNT) - mean * mean;
        float a = gamma[c] * rsqrtf(var + EPSV);
        a_out[c] = a;
        s_out[c] = beta[c] - mean * a;
    }
}

// ---------------------------------------------------------------- BN3+relu on z3 extremes
// out = relu(a3*zmax+s3) if a3>=0 else relu(a3*zmin+s3). Bit-identical to the
// full stage-4 recompute: *,+ by/with positive a and relu are fp-monotone.
__global__ __launch_bounds__(256) void apply_bn3(const float* __restrict__ zext,
                                                 const float* __restrict__ ab,
                                                 float* __restrict__ out_np) {
    int k = blockIdx.x * 256 + threadIdx.x;        // f4 index over (B*M, 128)
    if (k >= NGRP * 32) return;
    int g = k >> 5, q = k & 31;
    float4 mx = ((const float4*)zext)[g*64 + q];
    float4 mn = ((const float4*)zext)[g*64 + 32 + q];
    float4 a  = ((const float4*)ab)[64 + q];       // a3
    float4 s  = ((const float4*)ab)[96 + q];       // s3
    float4 r;
    r.x = fmaxf(a.x * (a.x >= 0.f ? mx.x : mn.x) + s.x, 0.f);
    r.y = fmaxf(a.y * (a.y >= 0.f ? mx.y : mn.y) + s.y, 0.f);
    r.z = fmaxf(a.z * (a.z >= 0.f ? mx.z : mn.z) + s.z, 0.f);
    r.w = fmaxf(a.w * (a.w >= 0.f ? mx.w : mn.w) + s.w, 0.f);
    ((float4*)out_np)[k] = r;
}

// ---------------------------------------------------------------- fused per-group chain
template<int STAGE>
__global__ __launch_bounds__(256, (STAGE <= 1) ? 4 : ((STAGE == 2) ? 2 : 1))
void chain_kernel(const float* __restrict__ xyz, const float* __restrict__ points,
                  const float* __restrict__ newxyz, const int* __restrict__ knn_idx,
                  const float4* __restrict__ wg,
                  const float* __restrict__ b1, const float* __restrict__ b2,
                  const float* __restrict__ b3, const float* __restrict__ ab,
                  float* __restrict__ gstats, float* __restrict__ out_np,
                  float* __restrict__ zext)
{
    constexpr int W1F4 = 17*64;                       // 1088
    constexpr int W2F4 = (STAGE >= 2) ? 16*64 : 0;    // 1024
    constexpr int W3F4 = (STAGE >= 3) ? 16*128 : 0;   // 2048
    constexpr int WTOT = W1F4 + W2F4 + W3F4;
    constexpr int FEATF4 = 32*24;                     // 768 (24 slots/row)
    constexpr int HBF4 = (STAGE >= 2) ? 32*16 : 0;    // 512 (16 slots/row)
    __shared__ __align__(16) float4 smem[WTOT + FEATF4 + HBF4 + 72];  // +72f4: stats(256f)+kidx(32i)
    float4* featb = smem + WTOT;
    float*  featF = (float*)featb;
    float4* hb    = featb + FEATF4;
    float*  hbF   = (float*)hb;
    float*  statL = (float*)(smem + WTOT + FEATF4 + HBF4);
    int*    kidx  = (int*)(statL + 256);

    const int t = threadIdx.x;
    const int rowg = t & 7;
    const int colg = t >> 3;

    for (int i = t; i < WTOT; i += 256) smem[i] = wg[i];
    if (STAGE < 4) statL[t] = 0.f;

    float bias1[2], a1v[2], s1v[2], bias2[2], a2v[2], s2v[2];
    float bias3[4], a3v[4], s3v[4];
#pragma unroll
    for (int j = 0; j < 2; ++j) {
        int c = colg + 32*j;
        bias1[j] = b1[c]; bias2[j] = b2[c];
        if (STAGE >= 2) { a1v[j] = ab[c];       s1v[j] = ab[64 + c]; }
        if (STAGE >= 3) { a2v[j] = ab[128 + c]; s2v[j] = ab[192 + c]; }
    }
#pragma unroll
    for (int j = 0; j < 4; ++j) {
        int c = colg + 32*j;
        bias3[j] = b3[c];
        if (STAGE == 4) { a3v[j] = ab[256 + c]; s3v[j] = ab[384 + c]; }
    }

    for (int g = blockIdx.x; g < NGRP; g += gridDim.x) {
        const int b = g >> 10;
        __syncthreads();                               // protect smem reuse across groups
        if (t < 32) kidx[t] = knn_idx[(size_t)g*NK + t];
        __syncthreads();
        const float* pb = points + (size_t)b * NP * CIN;
        {
            int r0 = t >> 4, c4g = t & 15;
            featb[r0*24 + (c4g ^ (r0>>2))] = *(const float4*)(pb + (size_t)kidx[r0]*CIN + c4g*4);
            int r1 = r0 + 16;
            featb[r1*24 + (c4g ^ (r1>>2))] = *(const float4*)(pb + (size_t)kidx[r1]*CIN + c4g*4);
        }
        const float* xb = xyz + (size_t)b * NP * 3;
        if (t < 96) {
            int r = t / 3, d = t - r*3;
            featF[r*96 + ((16 ^ (r>>2))<<2) + d] = xb[kidx[r]*3 + d] - newxyz[(size_t)g*3 + d];
        }
        if (t < 32) featF[t*96 + ((16 ^ (t>>2))<<2) + 3] = 0.f;
        __syncthreads();

        // ---- layer 1: K=68 (17 chunks)
        float acc[2][4];
#pragma unroll
        for (int i = 0; i < 4; ++i) { acc[0][i] = bias1[0]; acc[1][i] = bias1[1]; }
#pragma unroll 4
        for (int c4 = 0; c4 < 17; ++c4) {
            float4 w0 = smem[c4*64 + colg];
            float4 w1v = smem[c4*64 + colg + 32];
#pragma unroll
            for (int i = 0; i < 4; ++i) {
                float4 f = featb[(rowg*4 + i)*24 + (c4 ^ rowg)];
                acc[0][i] = dot4(f, w0, acc[0][i]);
                acc[1][i] = dot4(f, w1v, acc[1][i]);
            }
        }
        if (STAGE == 1) {
#pragma unroll
            for (int j = 0; j < 2; ++j) {
                float p = acc[j][0]+acc[j][1]+acc[j][2]+acc[j][3];
                float q = acc[j][0]*acc[j][0]+acc[j][1]*acc[j][1]+acc[j][2]*acc[j][2]+acc[j][3]*acc[j][3];
#pragma unroll
                for (int off = 4; off > 0; off >>= 1) { p += __shfl_down(p, off, 8); q += __shfl_down(q, off, 8); }
                if (rowg == 0) { int c = colg + 32*j; statL[c] += p; statL[128 + c] += q; }
            }
            continue;
        }
        // h1 -> hbuf
#pragma unroll
        for (int j = 0; j < 2; ++j) {
            int col = colg + 32*j;
            int so = (((col>>2) ^ rowg) << 2) + (col & 3);
#pragma unroll
            for (int i = 0; i < 4; ++i)
                hbF[(rowg*4 + i)*64 + so] = fmaxf(acc[j][i]*a1v[j] + s1v[j], 0.f);
        }
        __syncthreads();

        // ---- layer 2: K=64 (16 chunks), input hbuf
#pragma unroll
        for (int i = 0; i < 4; ++i) { acc[0][i] = bias2[0]; acc[1][i] = bias2[1]; }
#pragma unroll 4
        for (int c4 = 0; c4 < 16; ++c4) {
            float4 w0 = smem[W1F4 + c4*64 + colg];
            float4 w1v = smem[W1F4 + c4*64 + colg + 32];
#pragma unroll
            for (int i = 0; i < 4; ++i) {
                float4 f = hb[(rowg*4 + i)*16 + (c4 ^ rowg)];
                acc[0][i] = dot4(f, w0, acc[0][i]);
                acc[1][i] = dot4(f, w1v, acc[1][i]);
            }
        }
        if (STAGE == 2) {
#pragma unroll
            for (int j = 0; j < 2; ++j) {
                float p = acc[j][0]+acc[j][1]+acc[j][2]+acc[j][3];
                float q = acc[j][0]*acc[j][0]+acc[j][1]*acc[j][1]+acc[j][2]*acc[j][2]+acc[j][3]*acc[j][3];
#pragma unroll
                for (int off = 4; off > 0; off >>= 1) { p += __shfl_down(p, off, 8); q += __shfl_down(q, off, 8); }
                if (rowg == 0) { int c = colg + 32*j; statL[c] += p; statL[128 + c] += q; }
            }
            continue;
        }
        // h2 -> feat buffer (ping-pong)
#pragma unroll
        for (int j = 0; j < 2; ++j) {
            int col = colg + 32*j;
            int so = (((col>>2) ^ rowg) << 2) + (col & 3);
#pragma unroll
            for (int i = 0; i < 4; ++i)
                featF[(rowg*4 + i)*96 + so] = fmaxf(acc[j][i]*a2v[j] + s2v[j], 0.f);
        }
        __syncthreads();

        // ---- layer 3: K=64, 128 cols (TN=4), input feat buffer
        float acc3[4][4];
#pragma unroll
        for (int i = 0; i < 4; ++i)
#pragma unroll
            for (int j = 0; j < 4; ++j) acc3[j][i] = bias3[j];
#pragma unroll 4
        for (int c4 = 0; c4 < 16; ++c4) {
            float4 wa = smem[W1F4 + W2F4 + c4*128 + colg];
            float4 wb = smem[W1F4 + W2F4 + c4*128 + colg + 32];
            float4 wc = smem[W1F4 + W2F4 + c4*128 + colg + 64];
            float4 wd = smem[W1F4 + W2F4 + c4*128 + colg + 96];
#pragma unroll
            for (int i = 0; i < 4; ++i) {
                float4 f = featb[(rowg*4 + i)*24 + (c4 ^ rowg)];
                acc3[0][i] = dot4(f, wa, acc3[0][i]);
                acc3[1][i] = dot4(f, wb, acc3[1][i]);
                acc3[2][i] = dot4(f, wc, acc3[2][i]);
                acc3[3][i] = dot4(f, wd, acc3[3][i]);
            }
        }
        if (STAGE == 3) {
#pragma unroll
            for (int j = 0; j < 4; ++j) {
                float p = acc3[j][0]+acc3[j][1]+acc3[j][2]+acc3[j][3];
                float q = acc3[j][0]*acc3[j][0]+acc3[j][1]*acc3[j][1]+acc3[j][2]*acc3[j][2]+acc3[j][3]*acc3[j][3];
#pragma unroll
                for (int off = 4; off > 0; off >>= 1) { p += __shfl_down(p, off, 8); q += __shfl_down(q, off, 8); }
                if (rowg == 0) { int c = colg + 32*j; statL[c] += p; statL[128 + c] += q; }
            }
            if (zext) {   // per-group per-channel raw-z3 max/min -> stage 4 elimination
                float mx[4], mn[4];
#pragma unroll
                for (int j = 0; j < 4; ++j) {
                    mx[j] = fmaxf(fmaxf(acc3[j][0], acc3[j][1]), fmaxf(acc3[j][2], acc3[j][3]));
                    mn[j] = fminf(fminf(acc3[j][0], acc3[j][1]), fminf(acc3[j][2], acc3[j][3]));
                }
#pragma unroll
                for (int off = 4; off > 0; off >>= 1)
#pragma unroll
                    for (int j = 0; j < 4; ++j) {
                        mx[j] = fmaxf(mx[j], __shfl_down(mx[j], off, 8));
                        mn[j] = fminf(mn[j], __shfl_down(mn[j], off, 8));
                    }
                if (rowg == 0) {
#pragma unroll
                    for (int j = 0; j < 4; ++j) {
                        zext[(size_t)g*256 + colg + 32*j]       = mx[j];
                        zext[(size_t)g*256 + 128 + colg + 32*j] = mn[j];
                    }
                }
            }
            continue;
        }
        // ---- STAGE 4 (fallback only): bn+relu, max over 32 rows, write
        float mx[4];
#pragma unroll
        for (int j = 0; j < 4; ++j) {
            float h0 = fmaxf(acc3[j][0]*a3v[j] + s3v[j], 0.f);
            float h1 = fmaxf(acc3[j][1]*a3v[j] + s3v[j], 0.f);
            float h2 = fmaxf(acc3[j][2]*a3v[j] + s3v[j], 0.f);
            float h3 = fmaxf(acc3[j][3]*a3v[j] + s3v[j], 0.f);
            mx[j] = fmaxf(fmaxf(h0, h1), fmaxf(h2, h3));
        }
#pragma unroll
        for (int off = 4; off > 0; off >>= 1)
#pragma unroll
            for (int j = 0; j < 4; ++j) mx[j] = fmaxf(mx[j], __shfl_down(mx[j], off, 8));
        if (rowg == 0) {
#pragma unroll
            for (int j = 0; j < 4; ++j)
                out_np[(size_t)g*C3 + colg + 32*j] = mx[j];
        }
    }
    if (STAGE < 4) {
        __syncthreads();
        constexpr int C = (STAGE == 3) ? 128 : 64;
        if (t < C) { atomicAdd(&gstats[t], statL[t]); atomicAdd(&gstats[C + t], statL[128 + t]); }
    }
}

// ---------------------------------------------------------------- launch
extern "C" void kernel_launch(void* const* d_in, const int* in_sizes, int n_in,
                              void* d_out, int out_size, void* d_ws, size_t ws_size,
                              hipStream_t stream) {
    (void)in_sizes; (void)n_in; (void)out_size;
    const float* xyz    = (const float*)d_in[0];
    const float* points = (const float*)d_in[1];
    const float* w1  = (const float*)d_in[2];
    const float* b1  = (const float*)d_in[3];
    const float* g1  = (const float*)d_in[4];
    const float* be1 = (const float*)d_in[5];
    const float* w2  = (const float*)d_in[6];
    const float* b2  = (const float*)d_in[7];
    const float* g2  = (const float*)d_in[8];
    const float* be2 = (const float*)d_in[9];
    const float* w3  = (const float*)d_in[10];
    const float* b3  = (const float*)d_in[11];
    const float* g3  = (const float*)d_in[12];
    const float* be3 = (const float*)d_in[13];

    float* out = (float*)d_out;
    float* newxyz = out;                          // (B,M,3)
    float* out_np = out + (size_t)NB*NM*3;        // (B,M,128)

    int*    knn_idx = (int*)d_ws;                                 // 524288 ints
    float*  stats   = (float*)(knn_idx + (size_t)NB*NM*NK);       // 512 f
    float*  ab      = stats + 512;                                // 512 f
    float4* wg      = (float4*)(ab + 512);                        // 4160 f4
    float*  zext    = (float*)(wg + 4160);                        // 16384*256 f (16.8 MB)
    const size_t need = (size_t)((char*)(zext + (size_t)NGRP*256) - (char*)d_ws);
    const bool ext = ws_size >= need;
    float* zarg = ext ? zext : nullptr;

    hipMemsetAsync(stats, 0, 512*sizeof(float), stream);
    repack_weights<<<17, 256, 0, stream>>>(w1, w2, w3, wg);
    fps_kernel<<<NB, 256, 0, stream>>>(xyz, newxyz);
    knn_kernel<<<NB*NM, 256, 0, stream>>>(xyz, newxyz, knn_idx);

    chain_kernel<1><<<1024, 256, 0, stream>>>(xyz, points, newxyz, knn_idx, wg, b1, b2, b3,
                                              ab, stats + 0, out_np, nullptr);
    finalize_kernel<<<1, 64, 0, stream>>>(stats + 0, g1, be1, ab + 0, ab + 64, 64);
    chain_kernel<2><<<1024, 256, 0, stream>>>(xyz, points, newxyz, knn_idx, wg, b1, b2, b3,
                                              ab, stats + 128, out_np, nullptr);
    finalize_kernel<<<1, 64, 0, stream>>>(stats + 128, g2, be2, ab + 128, ab + 192, 64);
    chain_kernel<3><<<1024, 256, 0, stream>>>(xyz, points, newxyz, knn_idx, wg, b1, b2, b3,
                                              ab, stats + 256, out_np, zarg);
    finalize_kernel<<<1, 128, 0, stream>>>(stats + 256, g3, be3, ab + 256, ab + 384, 128);
    if (ext) {
        apply_bn3<<<2048, 256, 0, stream>>>(zext, ab, out_np);
    } else {
        chain_kernel<4><<<1024, 256, 0, stream>>>(xyz, points, newxyz, knn_idx, wg, b1, b2, b3,
                                                  ab, stats, out_np, nullptr);
    }
}

// Round 10
// 2423.372 us; speedup vs baseline: 4.8612x; 2.0913x over previous
//
#include <hip/hip_runtime.h>
#include <float.h>

#define NB 16
#define NP 4096
#define NM 1024
#define NK 32
#define CIN 64
#define C3 128
#define NGRP (NB*NM)
#define CNT (NB*NM*NK)
#define EPSV 1e-5f

// DPP cross-lane — used ONLY in knn (verified fast there; fps DPP/tree
// variants regressed 12x/4x in rounds 7/9 and were reverted).
#define DPPF(v, ctrl, rmask) __int_as_float(__builtin_amdgcn_update_dpp( \
        __float_as_int(v), __float_as_int(v), (ctrl), (rmask), 0xF, false))
#define DPPI(v, ctrl, rmask) __builtin_amdgcn_update_dpp((v), (v), (ctrl), (rmask), 0xF, false)

// Exact, contraction-free squared distance: matches numpy/JAX float32
// elementwise-square + left-to-right sum bit-for-bit (discrete selections
// in FPS/KNN depend on exact bit patterns).
__device__ __forceinline__ float sqdist3(float dx, float dy, float dz) {
    return __fadd_rn(__fadd_rn(__fmul_rn(dx, dx), __fmul_rn(dy, dy)), __fmul_rn(dz, dz));
}

__device__ __forceinline__ float dot4(float4 a, float4 b, float acc) {
    acc += a.x*b.x; acc += a.y*b.y; acc += a.z*b.z; acc += a.w*b.w; return acc;
}

// ---------------------------------------------------------------- FPS
// EXACT round-6 kernel (measured 875us; VGPR 64, SGPR 32). Serial if-chain
// local argmax carrying coords (compiler pipelines it via VCC cndmask —
// the "ILP tree" variant regressed 4x via SGPR mask pressure, r9 post-mortem).
// Value-only __shfl_xor butterfly, ballot/ffs winner, 3 shfl coord pulls,
// lane-0 parity-LDS store, one barrier, 4-way merge.
__global__ __launch_bounds__(256) void fps_kernel(const float* __restrict__ xyz,
                                                  float* __restrict__ newxyz) {
    const int b = blockIdx.x;
    const int t = threadIdx.x;
    const int lane = t & 63, wv = t >> 6;
    const float* xb = xyz + (size_t)b * NP * 3;

    float px[16], py[16], pz[16], dist[16];
    {   // vectorized one-time load: 48 consecutive floats per thread
        const float4* s4 = (const float4*)(xb + t * 48);
        float4 q[12];
#pragma unroll
        for (int j = 0; j < 12; ++j) q[j] = s4[j];
        const float* f = (const float*)q;
#pragma unroll
        for (int j = 0; j < 16; ++j) {
            px[j] = f[j*3+0]; py[j] = f[j*3+1]; pz[j] = f[j*3+2];
            dist[j] = 1e10f;
        }
    }
    __shared__ float4 red[2][4];
    float cx = xb[0], cy = xb[1], cz = xb[2];   // first centroid = point 0

    for (int it = 0; it < NM; ++it) {
        if (t == 0) {
            size_t o = ((size_t)b * NM + it) * 3;
            newxyz[o+0] = cx; newxyz[o+1] = cy; newxyz[o+2] = cz;
        }
        // update running min-dist, track local best value + its coords
        float best = -1.0f, bx = 0.f, by = 0.f, bz = 0.f;
#pragma unroll
        for (int j = 0; j < 16; ++j) {
            float d = sqdist3(px[j]-cx, py[j]-cy, pz[j]-cz);
            float nd = fminf(dist[j], d);
            dist[j] = nd;
            if (nd > best) { best = nd; bx = px[j]; by = py[j]; bz = pz[j]; }  // ascending j: lowest idx
        }
        // wave max (value only)
        float wmax = best;
#pragma unroll
        for (int off = 32; off > 0; off >>= 1)
            wmax = fmaxf(wmax, __shfl_xor(wmax, off, 64));
        // lowest lane holding the max == lowest global index in this wave
        unsigned long long mm = __ballot(best == wmax);
        int srcl = __ffsll((long long)mm) - 1;
        float wx = __shfl(bx, srcl, 64);
        float wy = __shfl(by, srcl, 64);
        float wz = __shfl(bz, srcl, 64);
        if (lane == 0) red[it & 1][wv] = make_float4(wmax, wx, wy, wz);
        __syncthreads();
        float4 r = red[it & 1][0];
        float bv = r.x; cx = r.y; cy = r.z; cz = r.w;
#pragma unroll
        for (int w = 1; w < 4; ++w) {
            float4 rw = red[it & 1][w];
            if (rw.x > bv) { bv = rw.x; cx = rw.y; cy = rw.z; cz = rw.w; }  // strict: lowest wave wins
        }
    }
}

// ---------------------------------------------------------------- KNN
// (round-7 verified) Dist slots in owning thread's registers -> no LDS dist
// array, one barrier per round (parity rv/ri). DPP pair-min reduce with
// explicit lowest-index tie-break (result in lane 63).
__global__ __launch_bounds__(256) void knn_kernel(const float* __restrict__ xyz,
                                                  const float* __restrict__ newxyz,
                                                  int* __restrict__ knn_idx) {
    const int g = blockIdx.x;
    const int b = g >> 10;
    const int t = threadIdx.x;
    const int lane = t & 63, wv = t >> 6;
    const float* xb = xyz + (size_t)b * NP * 3;
    __shared__ float rv[2][4];
    __shared__ int   ri[2][4];
    float cx = newxyz[(size_t)g*3+0], cy = newxyz[(size_t)g*3+1], cz = newxyz[(size_t)g*3+2];
    float dv[16];
#pragma unroll
    for (int j = 0; j < 16; ++j) {
        int n = t + 256*j;
        dv[j] = sqdist3(cx - xb[n*3+0], cy - xb[n*3+1], cz - xb[n*3+2]);
    }
    for (int s = 0; s < NK; ++s) {
        float tv[8]; int ti[8];
#pragma unroll
        for (int j = 0; j < 8; ++j) {
            bool tk = dv[2*j+1] < dv[2*j];
            tv[j] = tk ? dv[2*j+1] : dv[2*j];
            ti[j] = tk ? (2*j+1) : (2*j);
        }
#pragma unroll
        for (int j = 0; j < 4; ++j) {
            bool tk = tv[2*j+1] < tv[2*j];
            tv[j] = tk ? tv[2*j+1] : tv[2*j];
            ti[j] = tk ? ti[2*j+1] : ti[2*j];
        }
#pragma unroll
        for (int j = 0; j < 2; ++j) {
            bool tk = tv[2*j+1] < tv[2*j];
            tv[j] = tk ? tv[2*j+1] : tv[2*j];
            ti[j] = tk ? ti[2*j+1] : ti[2*j];
        }
        bool tkf = tv[1] < tv[0];
        float best = tkf ? tv[1] : tv[0];
        int   bi   = t + ((tkf ? ti[1] : ti[0]) << 8);
#define KSTEP(ctrl, rmask) { \
        float ov = DPPF(best, ctrl, rmask); \
        int   oi = DPPI(bi,   ctrl, rmask); \
        bool tk = (ov < best) || (ov == best && oi < bi); \
        best = tk ? ov : best; bi = tk ? oi : bi; }
        KSTEP(0x111, 0xF) KSTEP(0x112, 0xF) KSTEP(0x114, 0xF)
        KSTEP(0x118, 0xF) KSTEP(0x142, 0xA) KSTEP(0x143, 0xC)
#undef KSTEP
        if (lane == 63) { rv[s & 1][wv] = best; ri[s & 1][wv] = bi; }
        __syncthreads();
        float bv = rv[s & 1][0]; int bbi = ri[s & 1][0];
#pragma unroll
        for (int w = 1; w < 4; ++w) {
            float v2 = rv[s & 1][w]; int i2 = ri[s & 1][w];
            if (v2 < bv || (v2 == bv && i2 < bbi)) { bv = v2; bbi = i2; }
        }
        if (t == 0) knn_idx[(size_t)g*NK + s] = bbi;
        bool own = (bbi & 255) == t;
        int  jb  = bbi >> 8;
#pragma unroll
        for (int j = 0; j < 16; ++j)
            dv[j] = (own && (j == jb)) ? FLT_MAX : dv[j];
    }
}

// ---------------------------------------------------------------- weight pre-pack
__global__ void repack_weights(const float* __restrict__ w1, const float* __restrict__ w2,
                               const float* __restrict__ w3, float4* __restrict__ wg) {
    int id = threadIdx.x + blockIdx.x * 256;
    if (id >= 4160) return;
    float4 v;
    if (id < 1088) {
        int c4 = id >> 6, col = id & 63;
        float e[4];
#pragma unroll
        for (int l = 0; l < 4; ++l) {
            int c = c4*4 + l;
            e[l] = (c < 64) ? w1[col*67 + c + 3] : ((c < 67) ? w1[col*67 + (c - 64)] : 0.f);
        }
        v = make_float4(e[0], e[1], e[2], e[3]);
    } else if (id < 2112) {
        int i2 = id - 1088; int c4 = i2 >> 6, col = i2 & 63;
        const float* p = w2 + col*64 + c4*4;
        v = make_float4(p[0], p[1], p[2], p[3]);
    } else {
        int i3 = id - 2112; int c4 = i3 >> 7, col = i3 & 127;
        const float* p = w3 + col*64 + c4*4;
        v = make_float4(p[0], p[1], p[2], p[3]);
    }
    wg[id] = v;
}

// ---------------------------------------------------------------- BN finalize
__global__ void finalize_kernel(const float* __restrict__ gstats, const float* __restrict__ gamma,
                                const float* __restrict__ beta, float* __restrict__ a_out,
                                float* __restrict__ s_out, int C) {
    int c = threadIdx.x + blockIdx.x * blockDim.x;
    if (c < C) {
        float mean = gstats[c] * (1.0f / CNT);
        float var  = gstats[C + c] * (1.0f / CNT) - mean * mean;
        float a = gamma[c] * rsqrtf(var + EPSV);
        a_out[c] = a;
        s_out[c] = beta[c] - mean * a;
    }
}

// ---------------------------------------------------------------- BN3+relu on z3 extremes
// out = relu(a3*zmax+s3) if a3>=0 else relu(a3*zmin+s3). Bit-identical to the
// full stage-4 recompute: *,+ by/with positive a and relu are fp-monotone.
__global__ __launch_bounds__(256) void apply_bn3(const float* __restrict__ zext,
                                                 const float* __restrict__ ab,
                                                 float* __restrict__ out_np) {
    int k = blockIdx.x * 256 + threadIdx.x;        // f4 index over (B*M, 128)
    if (k >= NGRP * 32) return;
    int g = k >> 5, q = k & 31;
    float4 mx = ((const float4*)zext)[g*64 + q];
    float4 mn = ((const float4*)zext)[g*64 + 32 + q];
    float4 a  = ((const float4*)ab)[64 + q];       // a3
    float4 s  = ((const float4*)ab)[96 + q];       // s3
    float4 r;
    r.x = fmaxf(a.x * (a.x >= 0.f ? mx.x : mn.x) + s.x, 0.f);
    r.y = fmaxf(a.y * (a.y >= 0.f ? mx.y : mn.y) + s.y, 0.f);
    r.z = fmaxf(a.z * (a.z >= 0.f ? mx.z : mn.z) + s.z, 0.f);
    r.w = fmaxf(a.w * (a.w >= 0.f ? mx.w : mn.w) + s.w, 0.f);
    ((float4*)out_np)[k] = r;
}

// ---------------------------------------------------------------- fused per-group chain
template<int STAGE>
__global__ __launch_bounds__(256, (STAGE <= 1) ? 4 : ((STAGE == 2) ? 2 : 1))
void chain_kernel(const float* __restrict__ xyz, const float* __restrict__ points,
                  const float* __restrict__ newxyz, const int* __restrict__ knn_idx,
                  const float4* __restrict__ wg,
                  const float* __restrict__ b1, const float* __restrict__ b2,
                  const float* __restrict__ b3, const float* __restrict__ ab,
                  float* __restrict__ gstats, float* __restrict__ out_np,
                  float* __restrict__ zext)
{
    constexpr int W1F4 = 17*64;                       // 1088
    constexpr int W2F4 = (STAGE >= 2) ? 16*64 : 0;    // 1024
    constexpr int W3F4 = (STAGE >= 3) ? 16*128 : 0;   // 2048
    constexpr int WTOT = W1F4 + W2F4 + W3F4;
    constexpr int FEATF4 = 32*24;                     // 768 (24 slots/row)
    constexpr int HBF4 = (STAGE >= 2) ? 32*16 : 0;    // 512 (16 slots/row)
    __shared__ __align__(16) float4 smem[WTOT + FEATF4 + HBF4 + 72];  // +72f4: stats(256f)+kidx(32i)
    float4* featb = smem + WTOT;
    float*  featF = (float*)featb;
    float4* hb    = featb + FEATF4;
    float*  hbF   = (float*)hb;
    float*  statL = (float*)(smem + WTOT + FEATF4 + HBF4);
    int*    kidx  = (int*)(statL + 256);

    const int t = threadIdx.x;
    const int rowg = t & 7;
    const int colg = t >> 3;

    for (int i = t; i < WTOT; i += 256) smem[i] = wg[i];
    if (STAGE < 4) statL[t] = 0.f;

    float bias1[2], a1v[2], s1v[2], bias2[2], a2v[2], s2v[2];
    float bias3[4], a3v[4], s3v[4];
#pragma unroll
    for (int j = 0; j < 2; ++j) {
        int c = colg + 32*j;
        bias1[j] = b1[c]; bias2[j] = b2[c];
        if (STAGE >= 2) { a1v[j] = ab[c];       s1v[j] = ab[64 + c]; }
        if (STAGE >= 3) { a2v[j] = ab[128 + c]; s2v[j] = ab[192 + c]; }
    }
#pragma unroll
    for (int j = 0; j < 4; ++j) {
        int c = colg + 32*j;
        bias3[j] = b3[c];
        if (STAGE == 4) { a3v[j] = ab[256 + c]; s3v[j] = ab[384 + c]; }
    }

    for (int g = blockIdx.x; g < NGRP; g += gridDim.x) {
        const int b = g >> 10;
        __syncthreads();                               // protect smem reuse across groups
        if (t < 32) kidx[t] = knn_idx[(size_t)g*NK + t];
        __syncthreads();
        const float* pb = points + (size_t)b * NP * CIN;
        {
            int r0 = t >> 4, c4g = t & 15;
            featb[r0*24 + (c4g ^ (r0>>2))] = *(const float4*)(pb + (size_t)kidx[r0]*CIN + c4g*4);
            int r1 = r0 + 16;
            featb[r1*24 + (c4g ^ (r1>>2))] = *(const float4*)(pb + (size_t)kidx[r1]*CIN + c4g*4);
        }
        const float* xb = xyz + (size_t)b * NP * 3;
        if (t < 96) {
            int r = t / 3, d = t - r*3;
            featF[r*96 + ((16 ^ (r>>2))<<2) + d] = xb[kidx[r]*3 + d] - newxyz[(size_t)g*3 + d];
        }
        if (t < 32) featF[t*96 + ((16 ^ (t>>2))<<2) + 3] = 0.f;
        __syncthreads();

        // ---- layer 1: K=68 (17 chunks)
        float acc[2][4];
#pragma unroll
        for (int i = 0; i < 4; ++i) { acc[0][i] = bias1[0]; acc[1][i] = bias1[1]; }
#pragma unroll 4
        for (int c4 = 0; c4 < 17; ++c4) {
            float4 w0 = smem[c4*64 + colg];
            float4 w1v = smem[c4*64 + colg + 32];
#pragma unroll
            for (int i = 0; i < 4; ++i) {
                float4 f = featb[(rowg*4 + i)*24 + (c4 ^ rowg)];
                acc[0][i] = dot4(f, w0, acc[0][i]);
                acc[1][i] = dot4(f, w1v, acc[1][i]);
            }
        }
        if (STAGE == 1) {
#pragma unroll
            for (int j = 0; j < 2; ++j) {
                float p = acc[j][0]+acc[j][1]+acc[j][2]+acc[j][3];
                float q = acc[j][0]*acc[j][0]+acc[j][1]*acc[j][1]+acc[j][2]*acc[j][2]+acc[j][3]*acc[j][3];
#pragma unroll
                for (int off = 4; off > 0; off >>= 1) { p += __shfl_down(p, off, 8); q += __shfl_down(q, off, 8); }
                if (rowg == 0) { int c = colg + 32*j; statL[c] += p; statL[128 + c] += q; }
            }
            continue;
        }
        // h1 -> hbuf
#pragma unroll
        for (int j = 0; j < 2; ++j) {
            int col = colg + 32*j;
            int so = (((col>>2) ^ rowg) << 2) + (col & 3);
#pragma unroll
            for (int i = 0; i < 4; ++i)
                hbF[(rowg*4 + i)*64 + so] = fmaxf(acc[j][i]*a1v[j] + s1v[j], 0.f);
        }
        __syncthreads();

        // ---- layer 2: K=64 (16 chunks), input hbuf
#pragma unroll
        for (int i = 0; i < 4; ++i) { acc[0][i] = bias2[0]; acc[1][i] = bias2[1]; }
#pragma unroll 4
        for (int c4 = 0; c4 < 16; ++c4) {
            float4 w0 = smem[W1F4 + c4*64 + colg];
            float4 w1v = smem[W1F4 + c4*64 + colg + 32];
#pragma unroll
            for (int i = 0; i < 4; ++i) {
                float4 f = hb[(rowg*4 + i)*16 + (c4 ^ rowg)];
                acc[0][i] = dot4(f, w0, acc[0][i]);
                acc[1][i] = dot4(f, w1v, acc[1][i]);
            }
        }
        if (STAGE == 2) {
#pragma unroll
            for (int j = 0; j < 2; ++j) {
                float p = acc[j][0]+acc[j][1]+acc[j][2]+acc[j][3];
                float q = acc[j][0]*acc[j][0]+acc[j][1]*acc[j][1]+acc[j][2]*acc[j][2]+acc[j][3]*acc[j][3];
#pragma unroll
                for (int off = 4; off > 0; off >>= 1) { p += __shfl_down(p, off, 8); q += __shfl_down(q, off, 8); }
                if (rowg == 0) { int c = colg + 32*j; statL[c] += p; statL[128 + c] += q; }
            }
            continue;
        }
        // h2 -> feat buffer (ping-pong)
#pragma unroll
        for (int j = 0; j < 2; ++j) {
            int col = colg + 32*j;
            int so = (((col>>2) ^ rowg) << 2) + (col & 3);
#pragma unroll
            for (int i = 0; i < 4; ++i)
                featF[(rowg*4 + i)*96 + so] = fmaxf(acc[j][i]*a2v[j] + s2v[j], 0.f);
        }
        __syncthreads();

        // ---- layer 3: K=64, 128 cols (TN=4), input feat buffer
        float acc3[4][4];
#pragma unroll
        for (int i = 0; i < 4; ++i)
#pragma unroll
            for (int j = 0; j < 4; ++j) acc3[j][i] = bias3[j];
#pragma unroll 4
        for (int c4 = 0; c4 < 16; ++c4) {
            float4 wa = smem[W1F4 + W2F4 + c4*128 + colg];
            float4 wb = smem[W1F4 + W2F4 + c4*128 + colg + 32];
            float4 wc = smem[W1F4 + W2F4 + c4*128 + colg + 64];
            float4 wd = smem[W1F4 + W2F4 + c4*128 + colg + 96];
#pragma unroll
            for (int i = 0; i < 4; ++i) {
                float4 f = featb[(rowg*4 + i)*24 + (c4 ^ rowg)];
                acc3[0][i] = dot4(f, wa, acc3[0][i]);
                acc3[1][i] = dot4(f, wb, acc3[1][i]);
                acc3[2][i] = dot4(f, wc, acc3[2][i]);
                acc3[3][i] = dot4(f, wd, acc3[3][i]);
            }
        }
        if (STAGE == 3) {
#pragma unroll
            for (int j = 0; j < 4; ++j) {
                float p = acc3[j][0]+acc3[j][1]+acc3[j][2]+acc3[j][3];
                float q = acc3[j][0]*acc3[j][0]+acc3[j][1]*acc3[j][1]+acc3[j][2]*acc3[j][2]+acc3[j][3]*acc3[j][3];
#pragma unroll
                for (int off = 4; off > 0; off >>= 1) { p += __shfl_down(p, off, 8); q += __shfl_down(q, off, 8); }
                if (rowg == 0) { int c = colg + 32*j; statL[c] += p; statL[128 + c] += q; }
            }
            if (zext) {   // per-group per-channel raw-z3 max/min -> stage 4 elimination
                float mx[4], mn[4];
#pragma unroll
                for (int j = 0; j < 4; ++j) {
                    mx[j] = fmaxf(fmaxf(acc3[j][0], acc3[j][1]), fmaxf(acc3[j][2], acc3[j][3]));
                    mn[j] = fminf(fminf(acc3[j][0], acc3[j][1]), fminf(acc3[j][2], acc3[j][3]));
                }
#pragma unroll
                for (int off = 4; off > 0; off >>= 1)
#pragma unroll
                    for (int j = 0; j < 4; ++j) {
                        mx[j] = fmaxf(mx[j], __shfl_down(mx[j], off, 8));
                        mn[j] = fminf(mn[j], __shfl_down(mn[j], off, 8));
                    }
                if (rowg == 0) {
#pragma unroll
                    for (int j = 0; j < 4; ++j) {
                        zext[(size_t)g*256 + colg + 32*j]       = mx[j];
                        zext[(size_t)g*256 + 128 + colg + 32*j] = mn[j];
                    }
                }
            }
            continue;
        }
        // ---- STAGE 4 (fallback only): bn+relu, max over 32 rows, write
        float mx[4];
#pragma unroll
        for (int j = 0; j < 4; ++j) {
            float h0 = fmaxf(acc3[j][0]*a3v[j] + s3v[j], 0.f);
            float h1 = fmaxf(acc3[j][1]*a3v[j] + s3v[j], 0.f);
            float h2 = fmaxf(acc3[j][2]*a3v[j] + s3v[j], 0.f);
            float h3 = fmaxf(acc3[j][3]*a3v[j] + s3v[j], 0.f);
            mx[j] = fmaxf(fmaxf(h0, h1), fmaxf(h2, h3));
        }
#pragma unroll
        for (int off = 4; off > 0; off >>= 1)
#pragma unroll
            for (int j = 0; j < 4; ++j) mx[j] = fmaxf(mx[j], __shfl_down(mx[j], off, 8));
        if (rowg == 0) {
#pragma unroll
            for (int j = 0; j < 4; ++j)
                out_np[(size_t)g*C3 + colg + 32*j] = mx[j];
        }
    }
    if (STAGE < 4) {
        __syncthreads();
        constexpr int C = (STAGE == 3) ? 128 : 64;
        if (t < C) { atomicAdd(&gstats[t], statL[t]); atomicAdd(&gstats[C + t], statL[128 + t]); }
    }
}

// ---------------------------------------------------------------- launch
extern "C" void kernel_launch(void* const* d_in, const int* in_sizes, int n_in,
                              void* d_out, int out_size, void* d_ws, size_t ws_size,
                              hipStream_t stream) {
    (void)in_sizes; (void)n_in; (void)out_size;
    const float* xyz    = (const float*)d_in[0];
    const float* points = (const float*)d_in[1];
    const float* w1  = (const float*)d_in[2];
    const float* b1  = (const float*)d_in[3];
    const float* g1  = (const float*)d_in[4];
    const float* be1 = (const float*)d_in[5];
    const float* w2  = (const float*)d_in[6];
    const float* b2  = (const float*)d_in[7];
    const float* g2  = (const float*)d_in[8];
    const float* be2 = (const float*)d_in[9];
    const float* w3  = (const float*)d_in[10];
    const float* b3  = (const float*)d_in[11];
    const float* g3  = (const float*)d_in[12];
    const float* be3 = (const float*)d_in[13];

    float* out = (float*)d_out;
    float* newxyz = out;                          // (B,M,3)
    float* out_np = out + (size_t)NB*NM*3;        // (B,M,128)

    int*    knn_idx = (int*)d_ws;                                 // 524288 ints
    float*  stats   = (float*)(knn_idx + (size_t)NB*NM*NK);       // 512 f
    float*  ab      = stats + 512;                                // 512 f
    float4* wg      = (float4*)(ab + 512);                        // 4160 f4
    float*  zext    = (float*)(wg + 4160);                        // 16384*256 f (16.8 MB)
    const size_t need = (size_t)((char*)(zext + (size_t)NGRP*256) - (char*)d_ws);
    const bool ext = ws_size >= need;
    float* zarg = ext ? zext : nullptr;

    hipMemsetAsync(stats, 0, 512*sizeof(float), stream);
    repack_weights<<<17, 256, 0, stream>>>(w1, w2, w3, wg);
    fps_kernel<<<NB, 256, 0, stream>>>(xyz, newxyz);
    knn_kernel<<<NB*NM, 256, 0, stream>>>(xyz, newxyz, knn_idx);

    chain_kernel<1><<<1024, 256, 0, stream>>>(xyz, points, newxyz, knn_idx, wg, b1, b2, b3,
                                              ab, stats + 0, out_np, nullptr);
    finalize_kernel<<<1, 64, 0, stream>>>(stats + 0, g1, be1, ab + 0, ab + 64, 64);
    chain_kernel<2><<<1024, 256, 0, stream>>>(xyz, points, newxyz, knn_idx, wg, b1, b2, b3,
                                              ab, stats + 128, out_np, nullptr);
    finalize_kernel<<<1, 64, 0, stream>>>(stats + 128, g2, be2, ab + 128, ab + 192, 64);
    chain_kernel<3><<<1024, 256, 0, stream>>>(xyz, points, newxyz, knn_idx, wg, b1, b2, b3,
                                              ab, stats + 256, out_np, zarg);
    finalize_kernel<<<1, 128, 0, stream>>>(stats + 256, g3, be3, ab + 256, ab + 384, 128);
    if (ext) {
        apply_bn3<<<2048, 256, 0, stream>>>(zext, ab, out_np);
    } else {
        chain_kernel<4><<<1024, 256, 0, stream>>>(xyz, points, newxyz, knn_idx, wg, b1, b2, b3,
                                                  ab, stats, out_np, nullptr);
    }
}

// Round 11
// 1880.074 us; speedup vs baseline: 6.2659x; 1.2890x over previous
//
#include <hip/hip_runtime.h>
#include <float.h>

#define NB 16
#define NP 4096
#define NM 1024
#define NK 32
#define CIN 64
#define C3 128
#define NGRP (NB*NM)
#define CNT (NB*NM*NK)
#define EPSV 1e-5f

// DPP cross-lane — used ONLY in knn (verified fast there; fps DPP/tree
// variants regressed 12x/4x in rounds 7/9 and were reverted).
#define DPPF(v, ctrl, rmask) __int_as_float(__builtin_amdgcn_update_dpp( \
        __float_as_int(v), __float_as_int(v), (ctrl), (rmask), 0xF, false))
#define DPPI(v, ctrl, rmask) __builtin_amdgcn_update_dpp((v), (v), (ctrl), (rmask), 0xF, false)

// Exact, contraction-free squared distance: matches numpy/JAX float32
// elementwise-square + left-to-right sum bit-for-bit (discrete selections
// in FPS/KNN depend on exact bit patterns).
__device__ __forceinline__ float sqdist3(float dx, float dy, float dz) {
    return __fadd_rn(__fadd_rn(__fmul_rn(dx, dx), __fmul_rn(dy, dy)), __fmul_rn(dz, dz));
}

__device__ __forceinline__ float dot4(float4 a, float4 b, float acc) {
    acc += a.x*b.x; acc += a.y*b.y; acc += a.z*b.z; acc += a.w*b.w; return acc;
}

// ---------------------------------------------------------------- FPS
// EXACT round-6 kernel (measured 873us; VGPR 64, SGPR 32). Serial if-chain
// local argmax carrying coords (compiler pipelines it via VCC cndmask —
// the "ILP tree" variant regressed 4x via SGPR mask pressure, r9 post-mortem).
__global__ __launch_bounds__(256) void fps_kernel(const float* __restrict__ xyz,
                                                  float* __restrict__ newxyz) {
    const int b = blockIdx.x;
    const int t = threadIdx.x;
    const int lane = t & 63, wv = t >> 6;
    const float* xb = xyz + (size_t)b * NP * 3;

    float px[16], py[16], pz[16], dist[16];
    {   // vectorized one-time load: 48 consecutive floats per thread
        const float4* s4 = (const float4*)(xb + t * 48);
        float4 q[12];
#pragma unroll
        for (int j = 0; j < 12; ++j) q[j] = s4[j];
        const float* f = (const float*)q;
#pragma unroll
        for (int j = 0; j < 16; ++j) {
            px[j] = f[j*3+0]; py[j] = f[j*3+1]; pz[j] = f[j*3+2];
            dist[j] = 1e10f;
        }
    }
    __shared__ float4 red[2][4];
    float cx = xb[0], cy = xb[1], cz = xb[2];   // first centroid = point 0

    for (int it = 0; it < NM; ++it) {
        if (t == 0) {
            size_t o = ((size_t)b * NM + it) * 3;
            newxyz[o+0] = cx; newxyz[o+1] = cy; newxyz[o+2] = cz;
        }
        // update running min-dist, track local best value + its coords
        float best = -1.0f, bx = 0.f, by = 0.f, bz = 0.f;
#pragma unroll
        for (int j = 0; j < 16; ++j) {
            float d = sqdist3(px[j]-cx, py[j]-cy, pz[j]-cz);
            float nd = fminf(dist[j], d);
            dist[j] = nd;
            if (nd > best) { best = nd; bx = px[j]; by = py[j]; bz = pz[j]; }  // ascending j: lowest idx
        }
        // wave max (value only)
        float wmax = best;
#pragma unroll
        for (int off = 32; off > 0; off >>= 1)
            wmax = fmaxf(wmax, __shfl_xor(wmax, off, 64));
        // lowest lane holding the max == lowest global index in this wave
        unsigned long long mm = __ballot(best == wmax);
        int srcl = __ffsll((long long)mm) - 1;
        float wx = __shfl(bx, srcl, 64);
        float wy = __shfl(by, srcl, 64);
        float wz = __shfl(bz, srcl, 64);
        if (lane == 0) red[it & 1][wv] = make_float4(wmax, wx, wy, wz);
        __syncthreads();
        float4 r = red[it & 1][0];
        float bv = r.x; cx = r.y; cy = r.z; cz = r.w;
#pragma unroll
        for (int w = 1; w < 4; ++w) {
            float4 rw = red[it & 1][w];
            if (rw.x > bv) { bv = rw.x; cx = rw.y; cy = rw.z; cz = rw.w; }  // strict: lowest wave wins
        }
    }
}

// ---------------------------------------------------------------- KNN
// (round-7 verified) Dist slots in owning thread's registers; one barrier
// per round (parity rv/ri). DPP pair-min reduce, lowest-index tie-break.
__global__ __launch_bounds__(256) void knn_kernel(const float* __restrict__ xyz,
                                                  const float* __restrict__ newxyz,
                                                  int* __restrict__ knn_idx) {
    const int g = blockIdx.x;
    const int b = g >> 10;
    const int t = threadIdx.x;
    const int lane = t & 63, wv = t >> 6;
    const float* xb = xyz + (size_t)b * NP * 3;
    __shared__ float rv[2][4];
    __shared__ int   ri[2][4];
    float cx = newxyz[(size_t)g*3+0], cy = newxyz[(size_t)g*3+1], cz = newxyz[(size_t)g*3+2];
    float dv[16];
#pragma unroll
    for (int j = 0; j < 16; ++j) {
        int n = t + 256*j;
        dv[j] = sqdist3(cx - xb[n*3+0], cy - xb[n*3+1], cz - xb[n*3+2]);
    }
    for (int s = 0; s < NK; ++s) {
        float tv[8]; int ti[8];
#pragma unroll
        for (int j = 0; j < 8; ++j) {
            bool tk = dv[2*j+1] < dv[2*j];
            tv[j] = tk ? dv[2*j+1] : dv[2*j];
            ti[j] = tk ? (2*j+1) : (2*j);
        }
#pragma unroll
        for (int j = 0; j < 4; ++j) {
            bool tk = tv[2*j+1] < tv[2*j];
            tv[j] = tk ? tv[2*j+1] : tv[2*j];
            ti[j] = tk ? ti[2*j+1] : ti[2*j];
        }
#pragma unroll
        for (int j = 0; j < 2; ++j) {
            bool tk = tv[2*j+1] < tv[2*j];
            tv[j] = tk ? tv[2*j+1] : tv[2*j];
            ti[j] = tk ? ti[2*j+1] : ti[2*j];
        }
        bool tkf = tv[1] < tv[0];
        float best = tkf ? tv[1] : tv[0];
        int   bi   = t + ((tkf ? ti[1] : ti[0]) << 8);
#define KSTEP(ctrl, rmask) { \
        float ov = DPPF(best, ctrl, rmask); \
        int   oi = DPPI(bi,   ctrl, rmask); \
        bool tk = (ov < best) || (ov == best && oi < bi); \
        best = tk ? ov : best; bi = tk ? oi : bi; }
        KSTEP(0x111, 0xF) KSTEP(0x112, 0xF) KSTEP(0x114, 0xF)
        KSTEP(0x118, 0xF) KSTEP(0x142, 0xA) KSTEP(0x143, 0xC)
#undef KSTEP
        if (lane == 63) { rv[s & 1][wv] = best; ri[s & 1][wv] = bi; }
        __syncthreads();
        float bv = rv[s & 1][0]; int bbi = ri[s & 1][0];
#pragma unroll
        for (int w = 1; w < 4; ++w) {
            float v2 = rv[s & 1][w]; int i2 = ri[s & 1][w];
            if (v2 < bv || (v2 == bv && i2 < bbi)) { bv = v2; bbi = i2; }
        }
        if (t == 0) knn_idx[(size_t)g*NK + s] = bbi;
        bool own = (bbi & 255) == t;
        int  jb  = bbi >> 8;
#pragma unroll
        for (int j = 0; j < 16; ++j)
            dv[j] = (own && (j == jb)) ? FLT_MAX : dv[j];
    }
}

// ---------------------------------------------------------------- weight pre-pack
__global__ void repack_weights(const float* __restrict__ w1, const float* __restrict__ w2,
                               const float* __restrict__ w3, float4* __restrict__ wg) {
    int id = threadIdx.x + blockIdx.x * 256;
    if (id >= 4160) return;
    float4 v;
    if (id < 1088) {
        int c4 = id >> 6, col = id & 63;
        float e[4];
#pragma unroll
        for (int l = 0; l < 4; ++l) {
            int c = c4*4 + l;
            e[l] = (c < 64) ? w1[col*67 + c + 3] : ((c < 67) ? w1[col*67 + (c - 64)] : 0.f);
        }
        v = make_float4(e[0], e[1], e[2], e[3]);
    } else if (id < 2112) {
        int i2 = id - 1088; int c4 = i2 >> 6, col = i2 & 63;
        const float* p = w2 + col*64 + c4*4;
        v = make_float4(p[0], p[1], p[2], p[3]);
    } else {
        int i3 = id - 2112; int c4 = i3 >> 7, col = i3 & 127;
        const float* p = w3 + col*64 + c4*4;
        v = make_float4(p[0], p[1], p[2], p[3]);
    }
    wg[id] = v;
}

// ---------------------------------------------------------------- BN finalize
__global__ void finalize_kernel(const float* __restrict__ gstats, const float* __restrict__ gamma,
                                const float* __restrict__ beta, float* __restrict__ a_out,
                                float* __restrict__ s_out, int C) {
    int c = threadIdx.x + blockIdx.x * blockDim.x;
    if (c < C) {
        float mean = gstats[c] * (1.0f / CNT);
        float var  = gstats[C + c] * (1.0f / CNT) - mean * mean;
        float a = gamma[c] * rsqrtf(var + EPSV);
        a_out[c] = a;
        s_out[c] = beta[c] - mean * a;
    }
}

// ---------------------------------------------------------------- BN3+relu on z3 extremes
// out = relu(a3*zmax+s3) if a3>=0 else relu(a3*zmin+s3). Bit-identical to
// full recompute: *,+ and relu are fp-monotone.
__global__ __launch_bounds__(256) void apply_bn3(const float* __restrict__ zext,
                                                 const float* __restrict__ ab,
                                                 float* __restrict__ out_np) {
    int k = blockIdx.x * 256 + threadIdx.x;        // f4 index over (B*M, 128)
    if (k >= NGRP * 32) return;
    int g = k >> 5, q = k & 31;
    float4 mx = ((const float4*)zext)[g*64 + q];
    float4 mn = ((const float4*)zext)[g*64 + 32 + q];
    float4 a  = ((const float4*)ab)[64 + q];       // a3
    float4 s  = ((const float4*)ab)[96 + q];       // s3
    float4 r;
    r.x = fmaxf(a.x * (a.x >= 0.f ? mx.x : mn.x) + s.x, 0.f);
    r.y = fmaxf(a.y * (a.y >= 0.f ? mx.y : mn.y) + s.y, 0.f);
    r.z = fmaxf(a.z * (a.z >= 0.f ? mx.z : mn.z) + s.z, 0.f);
    r.w = fmaxf(a.w * (a.w >= 0.f ? mx.w : mn.w) + s.w, 0.f);
    ((float4*)out_np)[k] = r;
}

// ---------------------------------------------------------------- cached stage 2
// Reads own 8 raw-z1 values from zc (written by stage 1 by the SAME thread for
// the SAME group -> bit-exact), applies BN1+relu, LDS-stages h1, computes L2,
// accumulates z2 stats, overwrites zc with raw z2 in place.
// LDS: w2 (16KB) + hbuf (8KB) + stats. Skips gather + L1 entirely.
__global__ __launch_bounds__(256, 4) void chain2_cached(
    const float4* __restrict__ wg, const float* __restrict__ b2,
    const float* __restrict__ ab, float* __restrict__ gstats,
    float* __restrict__ zc)
{
    __shared__ __align__(16) float4 smem[1024 + 512 + 64];
    float4* hb  = smem + 1024;
    float*  hbF = (float*)hb;
    float*  statL = (float*)(smem + 1024 + 512);
    const int t = threadIdx.x;
    const int rowg = t & 7;
    const int colg = t >> 3;

    for (int i = t; i < 1024; i += 256) smem[i] = wg[1088 + i];
    statL[t] = 0.f;

    float a1v[2], s1v[2], bias2[2];
#pragma unroll
    for (int j = 0; j < 2; ++j) {
        int c = colg + 32*j;
        a1v[j] = ab[c]; s1v[j] = ab[64 + c]; bias2[j] = b2[c];
    }

    for (int g = blockIdx.x; g < NGRP; g += gridDim.x) {
        __syncthreads();                               // protect hbuf reuse
        float4* zp = (float4*)(zc + (size_t)g*2048 + t*8);
        float4 z0 = zp[0], z1 = zp[1];
        float za[2][4] = {{z0.x, z0.y, z0.z, z0.w}, {z1.x, z1.y, z1.z, z1.w}};
#pragma unroll
        for (int j = 0; j < 2; ++j) {
            int col = colg + 32*j;
            int so = (((col>>2) ^ rowg) << 2) + (col & 3);
#pragma unroll
            for (int i = 0; i < 4; ++i)
                hbF[(rowg*4 + i)*64 + so] = fmaxf(za[j][i]*a1v[j] + s1v[j], 0.f);
        }
        __syncthreads();

        float acc[2][4];
#pragma unroll
        for (int i = 0; i < 4; ++i) { acc[0][i] = bias2[0]; acc[1][i] = bias2[1]; }
#pragma unroll 4
        for (int c4 = 0; c4 < 16; ++c4) {
            float4 w0 = smem[c4*64 + colg];
            float4 w1v = smem[c4*64 + colg + 32];
#pragma unroll
            for (int i = 0; i < 4; ++i) {
                float4 f = hb[(rowg*4 + i)*16 + (c4 ^ rowg)];
                acc[0][i] = dot4(f, w0, acc[0][i]);
                acc[1][i] = dot4(f, w1v, acc[1][i]);
            }
        }
#pragma unroll
        for (int j = 0; j < 2; ++j) {
            float p = acc[j][0]+acc[j][1]+acc[j][2]+acc[j][3];
            float q = acc[j][0]*acc[j][0]+acc[j][1]*acc[j][1]+acc[j][2]*acc[j][2]+acc[j][3]*acc[j][3];
#pragma unroll
            for (int off = 4; off > 0; off >>= 1) { p += __shfl_down(p, off, 8); q += __shfl_down(q, off, 8); }
            if (rowg == 0) { int c = colg + 32*j; statL[c] += p; statL[128 + c] += q; }
        }
        zp[0] = make_float4(acc[0][0], acc[0][1], acc[0][2], acc[0][3]);   // raw z2 in place
        zp[1] = make_float4(acc[1][0], acc[1][1], acc[1][2], acc[1][3]);
    }
    __syncthreads();
    if (t < 64) { atomicAdd(&gstats[t], statL[t]); atomicAdd(&gstats[64 + t], statL[128 + t]); }
}

// ---------------------------------------------------------------- cached stage 3
// Reads own 8 raw-z2 values from zc, applies BN2+relu, LDS-stages h2,
// computes L3, accumulates z3 stats + per-group z3 max/min -> zext.
// LDS: w3 (32KB) + hbuf (8KB) + stats. Skips gather + L1 + L2.
__global__ __launch_bounds__(256, 3) void chain3_cached(
    const float4* __restrict__ wg, const float* __restrict__ b3,
    const float* __restrict__ ab, float* __restrict__ gstats,
    const float* __restrict__ zc, float* __restrict__ zext)
{
    __shared__ __align__(16) float4 smem[2048 + 512 + 64];
    float4* hb  = smem + 2048;
    float*  hbF = (float*)hb;
    float*  statL = (float*)(smem + 2048 + 512);
    const int t = threadIdx.x;
    const int rowg = t & 7;
    const int colg = t >> 3;

    for (int i = t; i < 2048; i += 256) smem[i] = wg[2112 + i];
    statL[t] = 0.f;

    float a2v[2], s2v[2], bias3[4];
#pragma unroll
    for (int j = 0; j < 2; ++j) {
        int c = colg + 32*j;
        a2v[j] = ab[128 + c]; s2v[j] = ab[192 + c];
    }
#pragma unroll
    for (int j = 0; j < 4; ++j) bias3[j] = b3[colg + 32*j];

    for (int g = blockIdx.x; g < NGRP; g += gridDim.x) {
        __syncthreads();                               // protect hbuf reuse
        const float4* zp = (const float4*)(zc + (size_t)g*2048 + t*8);
        float4 z0 = zp[0], z1 = zp[1];
        float za[2][4] = {{z0.x, z0.y, z0.z, z0.w}, {z1.x, z1.y, z1.z, z1.w}};
#pragma unroll
        for (int j = 0; j < 2; ++j) {
            int col = colg + 32*j;
            int so = (((col>>2) ^ rowg) << 2) + (col & 3);
#pragma unroll
            for (int i = 0; i < 4; ++i)
                hbF[(rowg*4 + i)*64 + so] = fmaxf(za[j][i]*a2v[j] + s2v[j], 0.f);
        }
        __syncthreads();

        float acc3[4][4];
#pragma unroll
        for (int i = 0; i < 4; ++i)
#pragma unroll
            for (int j = 0; j < 4; ++j) acc3[j][i] = bias3[j];
#pragma unroll 4
        for (int c4 = 0; c4 < 16; ++c4) {
            float4 wa = smem[c4*128 + colg];
            float4 wb = smem[c4*128 + colg + 32];
            float4 wc = smem[c4*128 + colg + 64];
            float4 wd = smem[c4*128 + colg + 96];
#pragma unroll
            for (int i = 0; i < 4; ++i) {
                float4 f = hb[(rowg*4 + i)*16 + (c4 ^ rowg)];
                acc3[0][i] = dot4(f, wa, acc3[0][i]);
                acc3[1][i] = dot4(f, wb, acc3[1][i]);
                acc3[2][i] = dot4(f, wc, acc3[2][i]);
                acc3[3][i] = dot4(f, wd, acc3[3][i]);
            }
        }
#pragma unroll
        for (int j = 0; j < 4; ++j) {
            float p = acc3[j][0]+acc3[j][1]+acc3[j][2]+acc3[j][3];
            float q = acc3[j][0]*acc3[j][0]+acc3[j][1]*acc3[j][1]+acc3[j][2]*acc3[j][2]+acc3[j][3]*acc3[j][3];
#pragma unroll
            for (int off = 4; off > 0; off >>= 1) { p += __shfl_down(p, off, 8); q += __shfl_down(q, off, 8); }
            if (rowg == 0) { int c = colg + 32*j; statL[c] += p; statL[128 + c] += q; }
        }
        float mx[4], mn[4];
#pragma unroll
        for (int j = 0; j < 4; ++j) {
            mx[j] = fmaxf(fmaxf(acc3[j][0], acc3[j][1]), fmaxf(acc3[j][2], acc3[j][3]));
            mn[j] = fminf(fminf(acc3[j][0], acc3[j][1]), fminf(acc3[j][2], acc3[j][3]));
        }
#pragma unroll
        for (int off = 4; off > 0; off >>= 1)
#pragma unroll
            for (int j = 0; j < 4; ++j) {
                mx[j] = fmaxf(mx[j], __shfl_down(mx[j], off, 8));
                mn[j] = fminf(mn[j], __shfl_down(mn[j], off, 8));
            }
        if (rowg == 0) {
#pragma unroll
            for (int j = 0; j < 4; ++j) {
                zext[(size_t)g*256 + colg + 32*j]       = mx[j];
                zext[(size_t)g*256 + 128 + colg + 32*j] = mn[j];
            }
        }
    }
    __syncthreads();
    if (t < 128) { atomicAdd(&gstats[t], statL[t]); atomicAdd(&gstats[128 + t], statL[128 + t]); }
}

// ---------------------------------------------------------------- fused per-group chain
// (r10-verified; fallback path + stage 1. Stage 1 optionally writes raw z1
// to zc for the cached pipeline.)
template<int STAGE>
__global__ __launch_bounds__(256, (STAGE <= 1) ? 4 : ((STAGE == 2) ? 2 : 1))
void chain_kernel(const float* __restrict__ xyz, const float* __restrict__ points,
                  const float* __restrict__ newxyz, const int* __restrict__ knn_idx,
                  const float4* __restrict__ wg,
                  const float* __restrict__ b1, const float* __restrict__ b2,
                  const float* __restrict__ b3, const float* __restrict__ ab,
                  float* __restrict__ gstats, float* __restrict__ out_np,
                  float* __restrict__ zext, float* __restrict__ zc)
{
    constexpr int W1F4 = 17*64;                       // 1088
    constexpr int W2F4 = (STAGE >= 2) ? 16*64 : 0;    // 1024
    constexpr int W3F4 = (STAGE >= 3) ? 16*128 : 0;   // 2048
    constexpr int WTOT = W1F4 + W2F4 + W3F4;
    constexpr int FEATF4 = 32*24;                     // 768 (24 slots/row)
    constexpr int HBF4 = (STAGE >= 2) ? 32*16 : 0;    // 512 (16 slots/row)
    __shared__ __align__(16) float4 smem[WTOT + FEATF4 + HBF4 + 72];  // +72f4: stats(256f)+kidx(32i)
    float4* featb = smem + WTOT;
    float*  featF = (float*)featb;
    float4* hb    = featb + FEATF4;
    float*  hbF   = (float*)hb;
    float*  statL = (float*)(smem + WTOT + FEATF4 + HBF4);
    int*    kidx  = (int*)(statL + 256);

    const int t = threadIdx.x;
    const int rowg = t & 7;
    const int colg = t >> 3;

    for (int i = t; i < WTOT; i += 256) smem[i] = wg[i];
    if (STAGE < 4) statL[t] = 0.f;

    float bias1[2], a1v[2], s1v[2], bias2[2], a2v[2], s2v[2];
    float bias3[4], a3v[4], s3v[4];
#pragma unroll
    for (int j = 0; j < 2; ++j) {
        int c = colg + 32*j;
        bias1[j] = b1[c]; bias2[j] = b2[c];
        if (STAGE >= 2) { a1v[j] = ab[c];       s1v[j] = ab[64 + c]; }
        if (STAGE >= 3) { a2v[j] = ab[128 + c]; s2v[j] = ab[192 + c]; }
    }
#pragma unroll
    for (int j = 0; j < 4; ++j) {
        int c = colg + 32*j;
        bias3[j] = b3[c];
        if (STAGE == 4) { a3v[j] = ab[256 + c]; s3v[j] = ab[384 + c]; }
    }

    for (int g = blockIdx.x; g < NGRP; g += gridDim.x) {
        const int b = g >> 10;
        __syncthreads();                               // protect smem reuse across groups
        if (t < 32) kidx[t] = knn_idx[(size_t)g*NK + t];
        __syncthreads();
        const float* pb = points + (size_t)b * NP * CIN;
        {
            int r0 = t >> 4, c4g = t & 15;
            featb[r0*24 + (c4g ^ (r0>>2))] = *(const float4*)(pb + (size_t)kidx[r0]*CIN + c4g*4);
            int r1 = r0 + 16;
            featb[r1*24 + (c4g ^ (r1>>2))] = *(const float4*)(pb + (size_t)kidx[r1]*CIN + c4g*4);
        }
        const float* xb = xyz + (size_t)b * NP * 3;
        if (t < 96) {
            int r = t / 3, d = t - r*3;
            featF[r*96 + ((16 ^ (r>>2))<<2) + d] = xb[kidx[r]*3 + d] - newxyz[(size_t)g*3 + d];
        }
        if (t < 32) featF[t*96 + ((16 ^ (t>>2))<<2) + 3] = 0.f;
        __syncthreads();

        // ---- layer 1: K=68 (17 chunks)
        float acc[2][4];
#pragma unroll
        for (int i = 0; i < 4; ++i) { acc[0][i] = bias1[0]; acc[1][i] = bias1[1]; }
#pragma unroll 4
        for (int c4 = 0; c4 < 17; ++c4) {
            float4 w0 = smem[c4*64 + colg];
            float4 w1v = smem[c4*64 + colg + 32];
#pragma unroll
            for (int i = 0; i < 4; ++i) {
                float4 f = featb[(rowg*4 + i)*24 + (c4 ^ rowg)];
                acc[0][i] = dot4(f, w0, acc[0][i]);
                acc[1][i] = dot4(f, w1v, acc[1][i]);
            }
        }
        if (STAGE == 1) {
#pragma unroll
            for (int j = 0; j < 2; ++j) {
                float p = acc[j][0]+acc[j][1]+acc[j][2]+acc[j][3];
                float q = acc[j][0]*acc[j][0]+acc[j][1]*acc[j][1]+acc[j][2]*acc[j][2]+acc[j][3]*acc[j][3];
#pragma unroll
                for (int off = 4; off > 0; off >>= 1) { p += __shfl_down(p, off, 8); q += __shfl_down(q, off, 8); }
                if (rowg == 0) { int c = colg + 32*j; statL[c] += p; statL[128 + c] += q; }
            }
            if (zc) {   // cache raw z1 for the cached pipeline
                float4* zp = (float4*)(zc + (size_t)g*2048 + t*8);
                zp[0] = make_float4(acc[0][0], acc[0][1], acc[0][2], acc[0][3]);
                zp[1] = make_float4(acc[1][0], acc[1][1], acc[1][2], acc[1][3]);
            }
            continue;
        }
        // h1 -> hbuf
#pragma unroll
        for (int j = 0; j < 2; ++j) {
            int col = colg + 32*j;
            int so = (((col>>2) ^ rowg) << 2) + (col & 3);
#pragma unroll
            for (int i = 0; i < 4; ++i)
                hbF[(rowg*4 + i)*64 + so] = fmaxf(acc[j][i]*a1v[j] + s1v[j], 0.f);
        }
        __syncthreads();

        // ---- layer 2: K=64 (16 chunks), input hbuf
#pragma unroll
        for (int i = 0; i < 4; ++i) { acc[0][i] = bias2[0]; acc[1][i] = bias2[1]; }
#pragma unroll 4
        for (int c4 = 0; c4 < 16; ++c4) {
            float4 w0 = smem[W1F4 + c4*64 + colg];
            float4 w1v = smem[W1F4 + c4*64 + colg + 32];
#pragma unroll
            for (int i = 0; i < 4; ++i) {
                float4 f = hb[(rowg*4 + i)*16 + (c4 ^ rowg)];
                acc[0][i] = dot4(f, w0, acc[0][i]);
                acc[1][i] = dot4(f, w1v, acc[1][i]);
            }
        }
        if (STAGE == 2) {
#pragma unroll
            for (int j = 0; j < 2; ++j) {
                float p = acc[j][0]+acc[j][1]+acc[j][2]+acc[j][3];
                float q = acc[j][0]*acc[j][0]+acc[j][1]*acc[j][1]+acc[j][2]*acc[j][2]+acc[j][3]*acc[j][3];
#pragma unroll
                for (int off = 4; off > 0; off >>= 1) { p += __shfl_down(p, off, 8); q += __shfl_down(q, off, 8); }
                if (rowg == 0) { int c = colg + 32*j; statL[c] += p; statL[128 + c] += q; }
            }
            continue;
        }
        // h2 -> feat buffer (ping-pong)
#pragma unroll
        for (int j = 0; j < 2; ++j) {
            int col = colg + 32*j;
            int so = (((col>>2) ^ rowg) << 2) + (col & 3);
#pragma unroll
            for (int i = 0; i < 4; ++i)
                featF[(rowg*4 + i)*96 + so] = fmaxf(acc[j][i]*a2v[j] + s2v[j], 0.f);
        }
        __syncthreads();

        // ---- layer 3: K=64, 128 cols (TN=4), input feat buffer
        float acc3[4][4];
#pragma unroll
        for (int i = 0; i < 4; ++i)
#pragma unroll
            for (int j = 0; j < 4; ++j) acc3[j][i] = bias3[j];
#pragma unroll 4
        for (int c4 = 0; c4 < 16; ++c4) {
            float4 wa = smem[W1F4 + W2F4 + c4*128 + colg];
            float4 wb = smem[W1F4 + W2F4 + c4*128 + colg + 32];
            float4 wc = smem[W1F4 + W2F4 + c4*128 + colg + 64];
            float4 wd = smem[W1F4 + W2F4 + c4*128 + colg + 96];
#pragma unroll
            for (int i = 0; i < 4; ++i) {
                float4 f = featb[(rowg*4 + i)*24 + (c4 ^ rowg)];
                acc3[0][i] = dot4(f, wa, acc3[0][i]);
                acc3[1][i] = dot4(f, wb, acc3[1][i]);
                acc3[2][i] = dot4(f, wc, acc3[2][i]);
                acc3[3][i] = dot4(f, wd, acc3[3][i]);
            }
        }
        if (STAGE == 3) {
#pragma unroll
            for (int j = 0; j < 4; ++j) {
                float p = acc3[j][0]+acc3[j][1]+acc3[j][2]+acc3[j][3];
                float q = acc3[j][0]*acc3[j][0]+acc3[j][1]*acc3[j][1]+acc3[j][2]*acc3[j][2]+acc3[j][3]*acc3[j][3];
#pragma unroll
                for (int off = 4; off > 0; off >>= 1) { p += __shfl_down(p, off, 8); q += __shfl_down(q, off, 8); }
                if (rowg == 0) { int c = colg + 32*j; statL[c] += p; statL[128 + c] += q; }
            }
            if (zext) {   // per-group per-channel raw-z3 max/min -> stage 4 elimination
                float mx[4], mn[4];
#pragma unroll
                for (int j = 0; j < 4; ++j) {
                    mx[j] = fmaxf(fmaxf(acc3[j][0], acc3[j][1]), fmaxf(acc3[j][2], acc3[j][3]));
                    mn[j] = fminf(fminf(acc3[j][0], acc3[j][1]), fminf(acc3[j][2], acc3[j][3]));
                }
#pragma unroll
                for (int off = 4; off > 0; off >>= 1)
#pragma unroll
                    for (int j = 0; j < 4; ++j) {
                        mx[j] = fmaxf(mx[j], __shfl_down(mx[j], off, 8));
                        mn[j] = fminf(mn[j], __shfl_down(mn[j], off, 8));
                    }
                if (rowg == 0) {
#pragma unroll
                    for (int j = 0; j < 4; ++j) {
                        zext[(size_t)g*256 + colg + 32*j]       = mx[j];
                        zext[(size_t)g*256 + 128 + colg + 32*j] = mn[j];
                    }
                }
            }
            continue;
        }
        // ---- STAGE 4 (fallback only): bn+relu, max over 32 rows, write
        float mx[4];
#pragma unroll
        for (int j = 0; j < 4; ++j) {
            float h0 = fmaxf(acc3[j][0]*a3v[j] + s3v[j], 0.f);
            float h1 = fmaxf(acc3[j][1]*a3v[j] + s3v[j], 0.f);
            float h2 = fmaxf(acc3[j][2]*a3v[j] + s3v[j], 0.f);
            float h3 = fmaxf(acc3[j][3]*a3v[j] + s3v[j], 0.f);
            mx[j] = fmaxf(fmaxf(h0, h1), fmaxf(h2, h3));
        }
#pragma unroll
        for (int off = 4; off > 0; off >>= 1)
#pragma unroll
            for (int j = 0; j < 4; ++j) mx[j] = fmaxf(mx[j], __shfl_down(mx[j], off, 8));
        if (rowg == 0) {
#pragma unroll
            for (int j = 0; j < 4; ++j)
                out_np[(size_t)g*C3 + colg + 32*j] = mx[j];
        }
    }
    if (STAGE < 4) {
        __syncthreads();
        constexpr int C = (STAGE == 3) ? 128 : 64;
        if (t < C) { atomicAdd(&gstats[t], statL[t]); atomicAdd(&gstats[C + t], statL[128 + t]); }
    }
}

// ---------------------------------------------------------------- launch
extern "C" void kernel_launch(void* const* d_in, const int* in_sizes, int n_in,
                              void* d_out, int out_size, void* d_ws, size_t ws_size,
                              hipStream_t stream) {
    (void)in_sizes; (void)n_in; (void)out_size;
    const float* xyz    = (const float*)d_in[0];
    const float* points = (const float*)d_in[1];
    const float* w1  = (const float*)d_in[2];
    const float* b1  = (const float*)d_in[3];
    const float* g1  = (const float*)d_in[4];
    const float* be1 = (const float*)d_in[5];
    const float* w2  = (const float*)d_in[6];
    const float* b2  = (const float*)d_in[7];
    const float* g2  = (const float*)d_in[8];
    const float* be2 = (const float*)d_in[9];
    const float* w3  = (const float*)d_in[10];
    const float* b3  = (const float*)d_in[11];
    const float* g3  = (const float*)d_in[12];
    const float* be3 = (const float*)d_in[13];

    float* out = (float*)d_out;
    float* newxyz = out;                          // (B,M,3)
    float* out_np = out + (size_t)NB*NM*3;        // (B,M,128)

    int*    knn_idx = (int*)d_ws;                                 // 524288 ints
    float*  stats   = (float*)(knn_idx + (size_t)NB*NM*NK);       // 512 f
    float*  ab      = stats + 512;                                // 512 f
    float4* wg      = (float4*)(ab + 512);                        // 4160 f4
    float*  zext    = (float*)(wg + 4160);                        // NGRP*256 f (16.8 MB)
    float*  zc      = zext + (size_t)NGRP*256;                    // NGRP*2048 f (134 MB)
    const size_t need1 = (size_t)((char*)zc - (char*)d_ws);
    const size_t need2 = (size_t)((char*)(zc + (size_t)NGRP*2048) - (char*)d_ws);
    const bool ext1 = ws_size >= need1;
    const bool ext2 = ws_size >= need2;
    float* zextArg = ext1 ? zext : nullptr;
    float* zcArg   = ext2 ? zc   : nullptr;

    hipMemsetAsync(stats, 0, 512*sizeof(float), stream);
    repack_weights<<<17, 256, 0, stream>>>(w1, w2, w3, wg);
    fps_kernel<<<NB, 256, 0, stream>>>(xyz, newxyz);
    knn_kernel<<<NB*NM, 256, 0, stream>>>(xyz, newxyz, knn_idx);

    chain_kernel<1><<<1024, 256, 0, stream>>>(xyz, points, newxyz, knn_idx, wg, b1, b2, b3,
                                              ab, stats + 0, out_np, nullptr, zcArg);
    finalize_kernel<<<1, 64, 0, stream>>>(stats + 0, g1, be1, ab + 0, ab + 64, 64);
    if (ext2) {
        chain2_cached<<<1024, 256, 0, stream>>>(wg, b2, ab, stats + 128, zc);
    } else {
        chain_kernel<2><<<1024, 256, 0, stream>>>(xyz, points, newxyz, knn_idx, wg, b1, b2, b3,
                                                  ab, stats + 128, out_np, nullptr, nullptr);
    }
    finalize_kernel<<<1, 64, 0, stream>>>(stats + 128, g2, be2, ab + 128, ab + 192, 64);
    if (ext2) {
        chain3_cached<<<1024, 256, 0, stream>>>(wg, b3, ab, stats + 256, zc, zext);
    } else {
        chain_kernel<3><<<1024, 256, 0, stream>>>(xyz, points, newxyz, knn_idx, wg, b1, b2, b3,
                                                  ab, stats + 256, out_np, zextArg, nullptr);
    }
    finalize_kernel<<<1, 128, 0, stream>>>(stats + 256, g3, be3, ab + 256, ab + 384, 128);
    if (ext1) {
        apply_bn3<<<2048, 256, 0, stream>>>(zext, ab, out_np);
    } else {
        chain_kernel<4><<<1024, 256, 0, stream>>>(xyz, points, newxyz, knn_idx, wg, b1, b2, b3,
                                                  ab, stats, out_np, nullptr, nullptr);
    }
}

// Round 12
// 1876.860 us; speedup vs baseline: 6.2767x; 1.0017x over previous
//
#include <hip/hip_runtime.h>
#include <float.h>

#define NB 16
#define NP 4096
#define NM 1024
#define NK 32
#define CIN 64
#define C3 128
#define NGRP (NB*NM)
#define CNT (NB*NM*NK)
#define EPSV 1e-5f

// DPP cross-lane (VALU ~8cyc vs ds_bpermute ~120cyc for __shfl).
// Verified fast+correct in knn's KSTEP since r7; fps now uses the SAME
// reduce shape (prefix shr 1/2/4/8 + bcast15/31, result in lane 63).
#define DPPF(v, ctrl, rmask) __int_as_float(__builtin_amdgcn_update_dpp( \
        __float_as_int(v), __float_as_int(v), (ctrl), (rmask), 0xF, false))
#define DPPI(v, ctrl, rmask) __builtin_amdgcn_update_dpp((v), (v), (ctrl), (rmask), 0xF, false)

// Exact, contraction-free squared distance: matches numpy/JAX float32
// elementwise-square + left-to-right sum bit-for-bit (discrete selections
// in FPS/KNN depend on exact bit patterns).
__device__ __forceinline__ float sqdist3(float dx, float dy, float dz) {
    return __fadd_rn(__fadd_rn(__fmul_rn(dx, dx), __fmul_rn(dy, dy)), __fmul_rn(dz, dz));
}

__device__ __forceinline__ float dot4(float4 a, float4 b, float acc) {
    acc += a.x*b.x; acc += a.y*b.y; acc += a.z*b.z; acc += a.w*b.w; return acc;
}

// ---------------------------------------------------------------- FPS
// r6-verified local argmax (serial VCC if-chain carrying coords; the ILP-tree
// variant regressed 4x — r9). Wave reduce now mirrors knn's VERIFIED DPP
// KSTEP: 6 steps carrying (val,x,y,z), lane-63 parity-LDS store, one barrier,
// 4-way merge. DPP incoming always covers strictly-LOWER indices, so
// 'ov >= best -> take' is the lowest-index tie-break; cross-wave merge uses
// strict '>' (lower wave = lower index).
__global__ __launch_bounds__(256) void fps_kernel(const float* __restrict__ xyz,
                                                  float* __restrict__ newxyz) {
    const int b = blockIdx.x;
    const int t = threadIdx.x;
    const int lane = t & 63, wv = t >> 6;
    const float* xb = xyz + (size_t)b * NP * 3;

    float px[16], py[16], pz[16], dist[16];
    {   // vectorized one-time load: 48 consecutive floats per thread
        const float4* s4 = (const float4*)(xb + t * 48);
        float4 q[12];
#pragma unroll
        for (int j = 0; j < 12; ++j) q[j] = s4[j];
        const float* f = (const float*)q;
#pragma unroll
        for (int j = 0; j < 16; ++j) {
            px[j] = f[j*3+0]; py[j] = f[j*3+1]; pz[j] = f[j*3+2];
            dist[j] = 1e10f;
        }
    }
    __shared__ float4 red[2][4];
    float cx = xb[0], cy = xb[1], cz = xb[2];   // first centroid = point 0

    for (int it = 0; it < NM; ++it) {
        if (t == 0) {
            size_t o = ((size_t)b * NM + it) * 3;
            newxyz[o+0] = cx; newxyz[o+1] = cy; newxyz[o+2] = cz;
        }
        // update running min-dist, track local best value + its coords
        float best = -1.0f, bx = 0.f, by = 0.f, bz = 0.f;
#pragma unroll
        for (int j = 0; j < 16; ++j) {
            float d = sqdist3(px[j]-cx, py[j]-cy, pz[j]-cz);
            float nd = fminf(dist[j], d);
            dist[j] = nd;
            if (nd > best) { best = nd; bx = px[j]; by = py[j]; bz = pz[j]; }  // ascending j: lowest idx
        }
        // wave argmax via DPP (knn-verified shape), coords carried
#define FSTEP(ctrl, rmask) { \
        float ov = DPPF(best, ctrl, rmask); \
        float ox = DPPF(bx,   ctrl, rmask); \
        float oy = DPPF(by,   ctrl, rmask); \
        float oz = DPPF(bz,   ctrl, rmask); \
        bool tk = (ov >= best); \
        best = tk ? ov : best; bx = tk ? ox : bx; \
        by   = tk ? oy : by;   bz = tk ? oz : bz; }
        FSTEP(0x111, 0xF) FSTEP(0x112, 0xF) FSTEP(0x114, 0xF)
        FSTEP(0x118, 0xF) FSTEP(0x142, 0xA) FSTEP(0x143, 0xC)
#undef FSTEP
        if (lane == 63) red[it & 1][wv] = make_float4(best, bx, by, bz);
        __syncthreads();
        float4 r = red[it & 1][0];
        float bv = r.x; cx = r.y; cy = r.z; cz = r.w;
#pragma unroll
        for (int w = 1; w < 4; ++w) {
            float4 rw = red[it & 1][w];
            if (rw.x > bv) { bv = rw.x; cx = rw.y; cy = rw.z; cz = rw.w; }  // strict: lowest wave wins
        }
    }
}

// ---------------------------------------------------------------- KNN
// (round-7 verified) Dist slots in owning thread's registers; one barrier
// per round (parity rv/ri). DPP pair-min reduce, lowest-index tie-break.
__global__ __launch_bounds__(256) void knn_kernel(const float* __restrict__ xyz,
                                                  const float* __restrict__ newxyz,
                                                  int* __restrict__ knn_idx) {
    const int g = blockIdx.x;
    const int b = g >> 10;
    const int t = threadIdx.x;
    const int lane = t & 63, wv = t >> 6;
    const float* xb = xyz + (size_t)b * NP * 3;
    __shared__ float rv[2][4];
    __shared__ int   ri[2][4];
    float cx = newxyz[(size_t)g*3+0], cy = newxyz[(size_t)g*3+1], cz = newxyz[(size_t)g*3+2];
    float dv[16];
#pragma unroll
    for (int j = 0; j < 16; ++j) {
        int n = t + 256*j;
        dv[j] = sqdist3(cx - xb[n*3+0], cy - xb[n*3+1], cz - xb[n*3+2]);
    }
    for (int s = 0; s < NK; ++s) {
        float tv[8]; int ti[8];
#pragma unroll
        for (int j = 0; j < 8; ++j) {
            bool tk = dv[2*j+1] < dv[2*j];
            tv[j] = tk ? dv[2*j+1] : dv[2*j];
            ti[j] = tk ? (2*j+1) : (2*j);
        }
#pragma unroll
        for (int j = 0; j < 4; ++j) {
            bool tk = tv[2*j+1] < tv[2*j];
            tv[j] = tk ? tv[2*j+1] : tv[2*j];
            ti[j] = tk ? ti[2*j+1] : ti[2*j];
        }
#pragma unroll
        for (int j = 0; j < 2; ++j) {
            bool tk = tv[2*j+1] < tv[2*j];
            tv[j] = tk ? tv[2*j+1] : tv[2*j];
            ti[j] = tk ? ti[2*j+1] : ti[2*j];
        }
        bool tkf = tv[1] < tv[0];
        float best = tkf ? tv[1] : tv[0];
        int   bi   = t + ((tkf ? ti[1] : ti[0]) << 8);
#define KSTEP(ctrl, rmask) { \
        float ov = DPPF(best, ctrl, rmask); \
        int   oi = DPPI(bi,   ctrl, rmask); \
        bool tk = (ov < best) || (ov == best && oi < bi); \
        best = tk ? ov : best; bi = tk ? oi : bi; }
        KSTEP(0x111, 0xF) KSTEP(0x112, 0xF) KSTEP(0x114, 0xF)
        KSTEP(0x118, 0xF) KSTEP(0x142, 0xA) KSTEP(0x143, 0xC)
#undef KSTEP
        if (lane == 63) { rv[s & 1][wv] = best; ri[s & 1][wv] = bi; }
        __syncthreads();
        float bv = rv[s & 1][0]; int bbi = ri[s & 1][0];
#pragma unroll
        for (int w = 1; w < 4; ++w) {
            float v2 = rv[s & 1][w]; int i2 = ri[s & 1][w];
            if (v2 < bv || (v2 == bv && i2 < bbi)) { bv = v2; bbi = i2; }
        }
        if (t == 0) knn_idx[(size_t)g*NK + s] = bbi;
        bool own = (bbi & 255) == t;
        int  jb  = bbi >> 8;
#pragma unroll
        for (int j = 0; j < 16; ++j)
            dv[j] = (own && (j == jb)) ? FLT_MAX : dv[j];
    }
}

// ---------------------------------------------------------------- weight pre-pack
__global__ void repack_weights(const float* __restrict__ w1, const float* __restrict__ w2,
                               const float* __restrict__ w3, float4* __restrict__ wg) {
    int id = threadIdx.x + blockIdx.x * 256;
    if (id >= 4160) return;
    float4 v;
    if (id < 1088) {
        int c4 = id >> 6, col = id & 63;
        float e[4];
#pragma unroll
        for (int l = 0; l < 4; ++l) {
            int c = c4*4 + l;
            e[l] = (c < 64) ? w1[col*67 + c + 3] : ((c < 67) ? w1[col*67 + (c - 64)] : 0.f);
        }
        v = make_float4(e[0], e[1], e[2], e[3]);
    } else if (id < 2112) {
        int i2 = id - 1088; int c4 = i2 >> 6, col = i2 & 63;
        const float* p = w2 + col*64 + c4*4;
        v = make_float4(p[0], p[1], p[2], p[3]);
    } else {
        int i3 = id - 2112; int c4 = i3 >> 7, col = i3 & 127;
        const float* p = w3 + col*64 + c4*4;
        v = make_float4(p[0], p[1], p[2], p[3]);
    }
    wg[id] = v;
}

// ---------------------------------------------------------------- BN finalize (fallback path + stage 3)
__global__ void finalize_kernel(const float* __restrict__ gstats, const float* __restrict__ gamma,
                                const float* __restrict__ beta, float* __restrict__ a_out,
                                float* __restrict__ s_out, int C) {
    int c = threadIdx.x + blockIdx.x * blockDim.x;
    if (c < C) {
        float mean = gstats[c] * (1.0f / CNT);
        float var  = gstats[C + c] * (1.0f / CNT) - mean * mean;
        float a = gamma[c] * rsqrtf(var + EPSV);
        a_out[c] = a;
        s_out[c] = beta[c] - mean * a;
    }
}

// ---------------------------------------------------------------- BN3+relu on z3 extremes
// out = relu(a3*zmax+s3) if a3>=0 else relu(a3*zmin+s3). Bit-identical to
// full recompute: *,+ and relu are fp-monotone.
__global__ __launch_bounds__(256) void apply_bn3(const float* __restrict__ zext,
                                                 const float* __restrict__ ab,
                                                 float* __restrict__ out_np) {
    int k = blockIdx.x * 256 + threadIdx.x;        // f4 index over (B*M, 128)
    if (k >= NGRP * 32) return;
    int g = k >> 5, q = k & 31;
    float4 mx = ((const float4*)zext)[g*64 + q];
    float4 mn = ((const float4*)zext)[g*64 + 32 + q];
    float4 a  = ((const float4*)ab)[64 + q];       // a3
    float4 s  = ((const float4*)ab)[96 + q];       // s3
    float4 r;
    r.x = fmaxf(a.x * (a.x >= 0.f ? mx.x : mn.x) + s.x, 0.f);
    r.y = fmaxf(a.y * (a.y >= 0.f ? mx.y : mn.y) + s.y, 0.f);
    r.z = fmaxf(a.z * (a.z >= 0.f ? mx.z : mn.z) + s.z, 0.f);
    r.w = fmaxf(a.w * (a.w >= 0.f ? mx.w : mn.w) + s.w, 0.f);
    ((float4*)out_np)[k] = r;
}

// ---------------------------------------------------------------- cached stage 2
// Computes a1/s1 per-thread from gstats1 (same fp expressions as
// finalize_kernel -> identical bits; saves a separate launch), reads own 8
// raw-z1 from zc, BN1+relu -> LDS h1 -> L2 -> z2 stats; z2 back in place.
__global__ __launch_bounds__(256, 4) void chain2_cached(
    const float4* __restrict__ wg, const float* __restrict__ b2,
    const float* __restrict__ gstats1, const float* __restrict__ g1,
    const float* __restrict__ be1, float* __restrict__ gstats,
    float* __restrict__ zc)
{
    __shared__ __align__(16) float4 smem[1024 + 512 + 64];
    float4* hb  = smem + 1024;
    float*  hbF = (float*)hb;
    float*  statL = (float*)(smem + 1024 + 512);
    const int t = threadIdx.x;
    const int rowg = t & 7;
    const int colg = t >> 3;

    for (int i = t; i < 1024; i += 256) smem[i] = wg[1088 + i];
    statL[t] = 0.f;

    float a1v[2], s1v[2], bias2[2];
#pragma unroll
    for (int j = 0; j < 2; ++j) {
        int c = colg + 32*j;
        float mean = gstats1[c] * (1.0f / CNT);
        float var  = gstats1[64 + c] * (1.0f / CNT) - mean * mean;
        float a = g1[c] * rsqrtf(var + EPSV);
        a1v[j] = a; s1v[j] = be1[c] - mean * a;
        bias2[j] = b2[c];
    }

    for (int g = blockIdx.x; g < NGRP; g += gridDim.x) {
        __syncthreads();                               // protect hbuf reuse
        float4* zp = (float4*)(zc + (size_t)g*2048 + t*8);
        float4 z0 = zp[0], z1 = zp[1];
        float za[2][4] = {{z0.x, z0.y, z0.z, z0.w}, {z1.x, z1.y, z1.z, z1.w}};
#pragma unroll
        for (int j = 0; j < 2; ++j) {
            int col = colg + 32*j;
            int so = (((col>>2) ^ rowg) << 2) + (col & 3);
#pragma unroll
            for (int i = 0; i < 4; ++i)
                hbF[(rowg*4 + i)*64 + so] = fmaxf(za[j][i]*a1v[j] + s1v[j], 0.f);
        }
        __syncthreads();

        float acc[2][4];
#pragma unroll
        for (int i = 0; i < 4; ++i) { acc[0][i] = bias2[0]; acc[1][i] = bias2[1]; }
#pragma unroll 4
        for (int c4 = 0; c4 < 16; ++c4) {
            float4 w0 = smem[c4*64 + colg];
            float4 w1v = smem[c4*64 + colg + 32];
#pragma unroll
            for (int i = 0; i < 4; ++i) {
                float4 f = hb[(rowg*4 + i)*16 + (c4 ^ rowg)];
                acc[0][i] = dot4(f, w0, acc[0][i]);
                acc[1][i] = dot4(f, w1v, acc[1][i]);
            }
        }
#pragma unroll
        for (int j = 0; j < 2; ++j) {
            float p = acc[j][0]+acc[j][1]+acc[j][2]+acc[j][3];
            float q = acc[j][0]*acc[j][0]+acc[j][1]*acc[j][1]+acc[j][2]*acc[j][2]+acc[j][3]*acc[j][3];
#pragma unroll
            for (int off = 4; off > 0; off >>= 1) { p += __shfl_down(p, off, 8); q += __shfl_down(q, off, 8); }
            if (rowg == 0) { int c = colg + 32*j; statL[c] += p; statL[128 + c] += q; }
        }
        zp[0] = make_float4(acc[0][0], acc[0][1], acc[0][2], acc[0][3]);   // raw z2 in place
        zp[1] = make_float4(acc[1][0], acc[1][1], acc[1][2], acc[1][3]);
    }
    __syncthreads();
    if (t < 64) { atomicAdd(&gstats[t], statL[t]); atomicAdd(&gstats[64 + t], statL[128 + t]); }
}

// ---------------------------------------------------------------- cached stage 3
// Computes a2/s2 per-thread from gstats2 (inlined finalize), reads own 8
// raw-z2 from zc, BN2+relu -> LDS h2 -> L3 -> z3 stats + per-group max/min.
__global__ __launch_bounds__(256, 3) void chain3_cached(
    const float4* __restrict__ wg, const float* __restrict__ b3,
    const float* __restrict__ gstats2, const float* __restrict__ g2,
    const float* __restrict__ be2, float* __restrict__ gstats,
    const float* __restrict__ zc, float* __restrict__ zext)
{
    __shared__ __align__(16) float4 smem[2048 + 512 + 64];
    float4* hb  = smem + 2048;
    float*  hbF = (float*)hb;
    float*  statL = (float*)(smem + 2048 + 512);
    const int t = threadIdx.x;
    const int rowg = t & 7;
    const int colg = t >> 3;

    for (int i = t; i < 2048; i += 256) smem[i] = wg[2112 + i];
    statL[t] = 0.f;

    float a2v[2], s2v[2], bias3[4];
#pragma unroll
    for (int j = 0; j < 2; ++j) {
        int c = colg + 32*j;
        float mean = gstats2[c] * (1.0f / CNT);
        float var  = gstats2[64 + c] * (1.0f / CNT) - mean * mean;
        float a = g2[c] * rsqrtf(var + EPSV);
        a2v[j] = a; s2v[j] = be2[c] - mean * a;
    }
#pragma unroll
    for (int j = 0; j < 4; ++j) bias3[j] = b3[colg + 32*j];

    for (int g = blockIdx.x; g < NGRP; g += gridDim.x) {
        __syncthreads();                               // protect hbuf reuse
        const float4* zp = (const float4*)(zc + (size_t)g*2048 + t*8);
        float4 z0 = zp[0], z1 = zp[1];
        float za[2][4] = {{z0.x, z0.y, z0.z, z0.w}, {z1.x, z1.y, z1.z, z1.w}};
#pragma unroll
        for (int j = 0; j < 2; ++j) {
            int col = colg + 32*j;
            int so = (((col>>2) ^ rowg) << 2) + (col & 3);
#pragma unroll
            for (int i = 0; i < 4; ++i)
                hbF[(rowg*4 + i)*64 + so] = fmaxf(za[j][i]*a2v[j] + s2v[j], 0.f);
        }
        __syncthreads();

        float acc3[4][4];
#pragma unroll
        for (int i = 0; i < 4; ++i)
#pragma unroll
            for (int j = 0; j < 4; ++j) acc3[j][i] = bias3[j];
#pragma unroll 4
        for (int c4 = 0; c4 < 16; ++c4) {
            float4 wa = smem[c4*128 + colg];
            float4 wb = smem[c4*128 + colg + 32];
            float4 wc = smem[c4*128 + colg + 64];
            float4 wd = smem[c4*128 + colg + 96];
#pragma unroll
            for (int i = 0; i < 4; ++i) {
                float4 f = hb[(rowg*4 + i)*16 + (c4 ^ rowg)];
                acc3[0][i] = dot4(f, wa, acc3[0][i]);
                acc3[1][i] = dot4(f, wb, acc3[1][i]);
                acc3[2][i] = dot4(f, wc, acc3[2][i]);
                acc3[3][i] = dot4(f, wd, acc3[3][i]);
            }
        }
#pragma unroll
        for (int j = 0; j < 4; ++j) {
            float p = acc3[j][0]+acc3[j][1]+acc3[j][2]+acc3[j][3];
            float q = acc3[j][0]*acc3[j][0]+acc3[j][1]*acc3[j][1]+acc3[j][2]*acc3[j][2]+acc3[j][3]*acc3[j][3];
#pragma unroll
            for (int off = 4; off > 0; off >>= 1) { p += __shfl_down(p, off, 8); q += __shfl_down(q, off, 8); }
            if (rowg == 0) { int c = colg + 32*j; statL[c] += p; statL[128 + c] += q; }
        }
        float mx[4], mn[4];
#pragma unroll
        for (int j = 0; j < 4; ++j) {
            mx[j] = fmaxf(fmaxf(acc3[j][0], acc3[j][1]), fmaxf(acc3[j][2], acc3[j][3]));
            mn[j] = fminf(fminf(acc3[j][0], acc3[j][1]), fminf(acc3[j][2], acc3[j][3]));
        }
#pragma unroll
        for (int off = 4; off > 0; off >>= 1)
#pragma unroll
            for (int j = 0; j < 4; ++j) {
                mx[j] = fmaxf(mx[j], __shfl_down(mx[j], off, 8));
                mn[j] = fminf(mn[j], __shfl_down(mn[j], off, 8));
            }
        if (rowg == 0) {
#pragma unroll
            for (int j = 0; j < 4; ++j) {
                zext[(size_t)g*256 + colg + 32*j]       = mx[j];
                zext[(size_t)g*256 + 128 + colg + 32*j] = mn[j];
            }
        }
    }
    __syncthreads();
    if (t < 128) { atomicAdd(&gstats[t], statL[t]); atomicAdd(&gstats[128 + t], statL[128 + t]); }
}

// ---------------------------------------------------------------- fused per-group chain
// (r10-verified; fallback path + stage 1. Stage 1 optionally writes raw z1
// to zc for the cached pipeline.)
template<int STAGE>
__global__ __launch_bounds__(256, (STAGE <= 1) ? 4 : ((STAGE == 2) ? 2 : 1))
void chain_kernel(const float* __restrict__ xyz, const float* __restrict__ points,
                  const float* __restrict__ newxyz, const int* __restrict__ knn_idx,
                  const float4* __restrict__ wg,
                  const float* __restrict__ b1, const float* __restrict__ b2,
                  const float* __restrict__ b3, const float* __restrict__ ab,
                  float* __restrict__ gstats, float* __restrict__ out_np,
                  float* __restrict__ zext, float* __restrict__ zc)
{
    constexpr int W1F4 = 17*64;                       // 1088
    constexpr int W2F4 = (STAGE >= 2) ? 16*64 : 0;    // 1024
    constexpr int W3F4 = (STAGE >= 3) ? 16*128 : 0;   // 2048
    constexpr int WTOT = W1F4 + W2F4 + W3F4;
    constexpr int FEATF4 = 32*24;                     // 768 (24 slots/row)
    constexpr int HBF4 = (STAGE >= 2) ? 32*16 : 0;    // 512 (16 slots/row)
    __shared__ __align__(16) float4 smem[WTOT + FEATF4 + HBF4 + 72];  // +72f4: stats(256f)+kidx(32i)
    float4* featb = smem + WTOT;
    float*  featF = (float*)featb;
    float4* hb    = featb + FEATF4;
    float*  hbF   = (float*)hb;
    float*  statL = (float*)(smem + WTOT + FEATF4 + HBF4);
    int*    kidx  = (int*)(statL + 256);

    const int t = threadIdx.x;
    const int rowg = t & 7;
    const int colg = t >> 3;

    for (int i = t; i < WTOT; i += 256) smem[i] = wg[i];
    if (STAGE < 4) statL[t] = 0.f;

    float bias1[2], a1v[2], s1v[2], bias2[2], a2v[2], s2v[2];
    float bias3[4], a3v[4], s3v[4];
#pragma unroll
    for (int j = 0; j < 2; ++j) {
        int c = colg + 32*j;
        bias1[j] = b1[c]; bias2[j] = b2[c];
        if (STAGE >= 2) { a1v[j] = ab[c];       s1v[j] = ab[64 + c]; }
        if (STAGE >= 3) { a2v[j] = ab[128 + c]; s2v[j] = ab[192 + c]; }
    }
#pragma unroll
    for (int j = 0; j < 4; ++j) {
        int c = colg + 32*j;
        bias3[j] = b3[c];
        if (STAGE == 4) { a3v[j] = ab[256 + c]; s3v[j] = ab[384 + c]; }
    }

    for (int g = blockIdx.x; g < NGRP; g += gridDim.x) {
        const int b = g >> 10;
        __syncthreads();                               // protect smem reuse across groups
        if (t < 32) kidx[t] = knn_idx[(size_t)g*NK + t];
        __syncthreads();
        const float* pb = points + (size_t)b * NP * CIN;
        {
            int r0 = t >> 4, c4g = t & 15;
            featb[r0*24 + (c4g ^ (r0>>2))] = *(const float4*)(pb + (size_t)kidx[r0]*CIN + c4g*4);
            int r1 = r0 + 16;
            featb[r1*24 + (c4g ^ (r1>>2))] = *(const float4*)(pb + (size_t)kidx[r1]*CIN + c4g*4);
        }
        const float* xb = xyz + (size_t)b * NP * 3;
        if (t < 96) {
            int r = t / 3, d = t - r*3;
            featF[r*96 + ((16 ^ (r>>2))<<2) + d] = xb[kidx[r]*3 + d] - newxyz[(size_t)g*3 + d];
        }
        if (t < 32) featF[t*96 + ((16 ^ (t>>2))<<2) + 3] = 0.f;
        __syncthreads();

        // ---- layer 1: K=68 (17 chunks)
        float acc[2][4];
#pragma unroll
        for (int i = 0; i < 4; ++i) { acc[0][i] = bias1[0]; acc[1][i] = bias1[1]; }
#pragma unroll 4
        for (int c4 = 0; c4 < 17; ++c4) {
            float4 w0 = smem[c4*64 + colg];
            float4 w1v = smem[c4*64 + colg + 32];
#pragma unroll
            for (int i = 0; i < 4; ++i) {
                float4 f = featb[(rowg*4 + i)*24 + (c4 ^ rowg)];
                acc[0][i] = dot4(f, w0, acc[0][i]);
                acc[1][i] = dot4(f, w1v, acc[1][i]);
            }
        }
        if (STAGE == 1) {
#pragma unroll
            for (int j = 0; j < 2; ++j) {
                float p = acc[j][0]+acc[j][1]+acc[j][2]+acc[j][3];
                float q = acc[j][0]*acc[j][0]+acc[j][1]*acc[j][1]+acc[j][2]*acc[j][2]+acc[j][3]*acc[j][3];
#pragma unroll
                for (int off = 4; off > 0; off >>= 1) { p += __shfl_down(p, off, 8); q += __shfl_down(q, off, 8); }
                if (rowg == 0) { int c = colg + 32*j; statL[c] += p; statL[128 + c] += q; }
            }
            if (zc) {   // cache raw z1 for the cached pipeline
                float4* zp = (float4*)(zc + (size_t)g*2048 + t*8);
                zp[0] = make_float4(acc[0][0], acc[0][1], acc[0][2], acc[0][3]);
                zp[1] = make_float4(acc[1][0], acc[1][1], acc[1][2], acc[1][3]);
            }
            continue;
        }
        // h1 -> hbuf
#pragma unroll
        for (int j = 0; j < 2; ++j) {
            int col = colg + 32*j;
            int so = (((col>>2) ^ rowg) << 2) + (col & 3);
#pragma unroll
            for (int i = 0; i < 4; ++i)
                hbF[(rowg*4 + i)*64 + so] = fmaxf(acc[j][i]*a1v[j] + s1v[j], 0.f);
        }
        __syncthreads();

        // ---- layer 2: K=64 (16 chunks), input hbuf
#pragma unroll
        for (int i = 0; i < 4; ++i) { acc[0][i] = bias2[0]; acc[1][i] = bias2[1]; }
#pragma unroll 4
        for (int c4 = 0; c4 < 16; ++c4) {
            float4 w0 = smem[W1F4 + c4*64 + colg];
            float4 w1v = smem[W1F4 + c4*64 + colg + 32];
#pragma unroll
            for (int i = 0; i < 4; ++i) {
                float4 f = hb[(rowg*4 + i)*16 + (c4 ^ rowg)];
                acc[0][i] = dot4(f, w0, acc[0][i]);
                acc[1][i] = dot4(f, w1v, acc[1][i]);
            }
        }
        if (STAGE == 2) {
#pragma unroll
            for (int j = 0; j < 2; ++j) {
                float p = acc[j][0]+acc[j][1]+acc[j][2]+acc[j][3];
                float q = acc[j][0]*acc[j][0]+acc[j][1]*acc[j][1]+acc[j][2]*acc[j][2]+acc[j][3]*acc[j][3];
#pragma unroll
                for (int off = 4; off > 0; off >>= 1) { p += __shfl_down(p, off, 8); q += __shfl_down(q, off, 8); }
                if (rowg == 0) { int c = colg + 32*j; statL[c] += p; statL[128 + c] += q; }
            }
            continue;
        }
        // h2 -> feat buffer (ping-pong)
#pragma unroll
        for (int j = 0; j < 2; ++j) {
            int col = colg + 32*j;
            int so = (((col>>2) ^ rowg) << 2) + (col & 3);
#pragma unroll
            for (int i = 0; i < 4; ++i)
                featF[(rowg*4 + i)*96 + so] = fmaxf(acc[j][i]*a2v[j] + s2v[j], 0.f);
        }
        __syncthreads();

        // ---- layer 3: K=64, 128 cols (TN=4), input feat buffer
        float acc3[4][4];
#pragma unroll
        for (int i = 0; i < 4; ++i)
#pragma unroll
            for (int j = 0; j < 4; ++j) acc3[j][i] = bias3[j];
#pragma unroll 4
        for (int c4 = 0; c4 < 16; ++c4) {
            float4 wa = smem[W1F4 + W2F4 + c4*128 + colg];
            float4 wb = smem[W1F4 + W2F4 + c4*128 + colg + 32];
            float4 wc = smem[W1F4 + W2F4 + c4*128 + colg + 64];
            float4 wd = smem[W1F4 + W2F4 + c4*128 + colg + 96];
#pragma unroll
            for (int i = 0; i < 4; ++i) {
                float4 f = featb[(rowg*4 + i)*24 + (c4 ^ rowg)];
                acc3[0][i] = dot4(f, wa, acc3[0][i]);
                acc3[1][i] = dot4(f, wb, acc3[1][i]);
                acc3[2][i] = dot4(f, wc, acc3[2][i]);
                acc3[3][i] = dot4(f, wd, acc3[3][i]);
            }
        }
        if (STAGE == 3) {
#pragma unroll
            for (int j = 0; j < 4; ++j) {
                float p = acc3[j][0]+acc3[j][1]+acc3[j][2]+acc3[j][3];
                float q = acc3[j][0]*acc3[j][0]+acc3[j][1]*acc3[j][1]+acc3[j][2]*acc3[j][2]+acc3[j][3]*acc3[j][3];
#pragma unroll
                for (int off = 4; off > 0; off >>= 1) { p += __shfl_down(p, off, 8); q += __shfl_down(q, off, 8); }
                if (rowg == 0) { int c = colg + 32*j; statL[c] += p; statL[128 + c] += q; }
            }
            if (zext) {   // per-group per-channel raw-z3 max/min -> stage 4 elimination
                float mx[4], mn[4];
#pragma unroll
                for (int j = 0; j < 4; ++j) {
                    mx[j] = fmaxf(fmaxf(acc3[j][0], acc3[j][1]), fmaxf(acc3[j][2], acc3[j][3]));
                    mn[j] = fminf(fminf(acc3[j][0], acc3[j][1]), fminf(acc3[j][2], acc3[j][3]));
                }
#pragma unroll
                for (int off = 4; off > 0; off >>= 1)
#pragma unroll
                    for (int j = 0; j < 4; ++j) {
                        mx[j] = fmaxf(mx[j], __shfl_down(mx[j], off, 8));
                        mn[j] = fminf(mn[j], __shfl_down(mn[j], off, 8));
                    }
                if (rowg == 0) {
#pragma unroll
                    for (int j = 0; j < 4; ++j) {
                        zext[(size_t)g*256 + colg + 32*j]       = mx[j];
                        zext[(size_t)g*256 + 128 + colg + 32*j] = mn[j];
                    }
                }
            }
            continue;
        }
        // ---- STAGE 4 (fallback only): bn+relu, max over 32 rows, write
        float mx[4];
#pragma unroll
        for (int j = 0; j < 4; ++j) {
            float h0 = fmaxf(acc3[j][0]*a3v[j] + s3v[j], 0.f);
            float h1 = fmaxf(acc3[j][1]*a3v[j] + s3v[j], 0.f);
            float h2 = fmaxf(acc3[j][2]*a3v[j] + s3v[j], 0.f);
            float h3 = fmaxf(acc3[j][3]*a3v[j] + s3v[j], 0.f);
            mx[j] = fmaxf(fmaxf(h0, h1), fmaxf(h2, h3));
        }
#pragma unroll
        for (int off = 4; off > 0; off >>= 1)
#pragma unroll
            for (int j = 0; j < 4; ++j) mx[j] = fmaxf(mx[j], __shfl_down(mx[j], off, 8));
        if (rowg == 0) {
#pragma unroll
            for (int j = 0; j < 4; ++j)
                out_np[(size_t)g*C3 + colg + 32*j] = mx[j];
        }
    }
    if (STAGE < 4) {
        __syncthreads();
        constexpr int C = (STAGE == 3) ? 128 : 64;
        if (t < C) { atomicAdd(&gstats[t], statL[t]); atomicAdd(&gstats[C + t], statL[128 + t]); }
    }
}

// ---------------------------------------------------------------- launch
extern "C" void kernel_launch(void* const* d_in, const int* in_sizes, int n_in,
                              void* d_out, int out_size, void* d_ws, size_t ws_size,
                              hipStream_t stream) {
    (void)in_sizes; (void)n_in; (void)out_size;
    const float* xyz    = (const float*)d_in[0];
    const float* points = (const float*)d_in[1];
    const float* w1  = (const float*)d_in[2];
    const float* b1  = (const float*)d_in[3];
    const float* g1  = (const float*)d_in[4];
    const float* be1 = (const float*)d_in[5];
    const float* w2  = (const float*)d_in[6];
    const float* b2  = (const float*)d_in[7];
    const float* g2  = (const float*)d_in[8];
    const float* be2 = (const float*)d_in[9];
    const float* w3  = (const float*)d_in[10];
    const float* b3  = (const float*)d_in[11];
    const float* g3  = (const float*)d_in[12];
    const float* be3 = (const float*)d_in[13];

    float* out = (float*)d_out;
    float* newxyz = out;                          // (B,M,3)
    float* out_np = out + (size_t)NB*NM*3;        // (B,M,128)

    int*    knn_idx = (int*)d_ws;                                 // 524288 ints
    float*  stats   = (float*)(knn_idx + (size_t)NB*NM*NK);       // 512 f
    float*  ab      = stats + 512;                                // 512 f
    float4* wg      = (float4*)(ab + 512);                        // 4160 f4
    float*  zext    = (float*)(wg + 4160);                        // NGRP*256 f (16.8 MB)
    float*  zc      = zext + (size_t)NGRP*256;                    // NGRP*2048 f (134 MB)
    const size_t need1 = (size_t)((char*)zc - (char*)d_ws);
    const size_t need2 = (size_t)((char*)(zc + (size_t)NGRP*2048) - (char*)d_ws);
    const bool ext1 = ws_size >= need1;
    const bool ext2 = ws_size >= need2;
    float* zextArg = ext1 ? zext : nullptr;
    float* zcArg   = ext2 ? zc   : nullptr;

    hipMemsetAsync(stats, 0, 512*sizeof(float), stream);
    repack_weights<<<17, 256, 0, stream>>>(w1, w2, w3, wg);
    fps_kernel<<<NB, 256, 0, stream>>>(xyz, newxyz);
    knn_kernel<<<NB*NM, 256, 0, stream>>>(xyz, newxyz, knn_idx);

    chain_kernel<1><<<1024, 256, 0, stream>>>(xyz, points, newxyz, knn_idx, wg, b1, b2, b3,
                                              ab, stats + 0, out_np, nullptr, zcArg);
    if (ext2) {
        chain2_cached<<<1024, 256, 0, stream>>>(wg, b2, stats + 0, g1, be1, stats + 128, zc);
        chain3_cached<<<1024, 256, 0, stream>>>(wg, b3, stats + 128, g2, be2, stats + 256, zc, zext);
    } else {
        finalize_kernel<<<1, 64, 0, stream>>>(stats + 0, g1, be1, ab + 0, ab + 64, 64);
        chain_kernel<2><<<1024, 256, 0, stream>>>(xyz, points, newxyz, knn_idx, wg, b1, b2, b3,
                                                  ab, stats + 128, out_np, nullptr, nullptr);
        finalize_kernel<<<1, 64, 0, stream>>>(stats + 128, g2, be2, ab + 128, ab + 192, 64);
        chain_kernel<3><<<1024, 256, 0, stream>>>(xyz, points, newxyz, knn_idx, wg, b1, b2, b3,
                                                  ab, stats + 256, out_np, zextArg, nullptr);
    }
    finalize_kernel<<<1, 128, 0, stream>>>(stats + 256, g3, be3, ab + 256, ab + 384, 128);
    if (ext1) {
        apply_bn3<<<2048, 256, 0, stream>>>(zext, ab, out_np);
    } else {
        chain_kernel<4><<<1024, 256, 0, stream>>>(xyz, points, newxyz, knn_idx, wg, b1, b2, b3,
                                                  ab, stats, out_np, nullptr, nullptr);
    }
}